// Round 5
// baseline (478.837 us; speedup 1.0000x reference)
//
#include <hip/hip_runtime.h>
#include <hip/hip_bf16.h>
#include <math.h>

#define NPTS  8192
#define DIM   512
#define KNNK  15
#define NCAND 22      // approx candidates kept for exact refine (bf16-screen safe margin)
#define NPAIR 105
#define CINF  3.0e38f

// knn tiling (R2-verified geometry): 128 x 1024 per block, grid 64x8
#define NI      128
#define NJSPLIT 8
#define NJ      (NPTS/NJSPLIT)   // 1024
#define JS      128
#define NSUB    (NJ/JS)          // 8
#define BK      32
#define NCH     (DIM/BK)         // 16 chunks, double-buffered
#define SDW     68               // packed sdist row stride in dwords (64 data + 4 pad)

// knn LDS byte map (39936 B):
//   staging buf0 [0,16384) buf1 [16384,32768)  (A[128][32] + B[128][32] bf16 each)
//   sdist packed bf16 [0,34816) aliases staging (disjoint lifetime)
#define BUF0_OFF   0
#define BUF1_OFF   16384
#define SQJ_OFF    34816
#define TLS_OFF    38912
#define KNN_LDS    39936

typedef __attribute__((ext_vector_type(8))) short short8;
typedef __attribute__((ext_vector_type(4))) float f32x4;

static __device__ __forceinline__ float wave_sum_f(float v) {
#pragma unroll
  for (int m = 32; m > 0; m >>= 1) v += __shfl_xor(v, m, 64);
  return v;
}

static __device__ __forceinline__ void load_lds16(const void* g, void* l) {
  __builtin_amdgcn_global_load_lds(
      (const __attribute__((address_space(1))) void*)g,
      (__attribute__((address_space(3))) void*)l, 16, 0, 0);
}

static __device__ __forceinline__ void bf16split(float x, short& h, short& l) {
  __hip_bfloat16 hb = __float2bfloat16(x);
  const float hf = __bfloat162float(hb);
  __hip_bfloat16 lb = __float2bfloat16(x - hf);
  h = *(short*)&hb;
  l = *(short*)&lb;
}

// ---------------------------------------------------------------- prep
// EA = bf16(-sqrt2 * E), EB = bf16(+sqrt2 * E): screen MFMA yields -2*dot
// directly so acc can be initialized with sqn_j (no writeback fma).
__global__ __launch_bounds__(256) void prep_kernel(
    const float* __restrict__ E, float* __restrict__ sqn,
    ushort* __restrict__ EA, ushort* __restrict__ EB) {
  const int row  = blockIdx.x * 4 + (threadIdx.x >> 6);
  const int lane = threadIdx.x & 63;
  const float SR2 = 1.4142135623730951f;
  float s = 0.f;
#pragma unroll
  for (int c = 0; c < 8; ++c) {
    const int d0 = lane + 64 * c;
    const float x = E[(size_t)row * DIM + d0];
    s = fmaf(x, x, s);
    __hip_bfloat16 ha = __float2bfloat16(-SR2 * x);
    __hip_bfloat16 hb = __float2bfloat16( SR2 * x);
    EA[(size_t)row * DIM + d0] = *(ushort*)&ha;
    EB[(size_t)row * DIM + d0] = *(ushort*)&hb;
  }
  s = wave_sum_f(s);
  if (lane == 0) sqn[row] = s;
}

// ---------------------------------------------------------------- knn
// R5 = R2-verified kernel + counted-vmcnt double buffer:
//   stage(t+1) -> s_waitcnt vmcnt(4) -> s_barrier   (stage(t) ready,
//     the 4 just-issued loads stay in flight across the barrier)
//   ds_read frags -> MFMA -> s_barrier               (reads done before
//     next iteration's stage-issue overwrites this buffer)
// vmcnt(0) only at the last chunk. This removes the per-chunk prefetch
// drain that __syncthreads (vmcnt(0)) imposed in R2.
__global__ __launch_bounds__(256, 4) void knn_kernel(
    const ushort* __restrict__ EA, const ushort* __restrict__ EB,
    const float* __restrict__ sqn,
    float* __restrict__ cd, int* __restrict__ ci) {
  __shared__ __align__(16) char sm[KNN_LDS];
  uint*  sdp  = (uint*)sm;                 // packed bf16-pair screen tile
  float* sqjs = (float*)(sm + SQJ_OFF);
  float* tls  = (float*)(sm + TLS_OFF);

  const int tid = threadIdx.x;
  const int w   = tid >> 6;
  const int L   = tid & 63;
  const int wr  = (w >> 1) & 1;        // i-half
  const int wc  = w & 1;               // j-half
  const int i0  = blockIdx.x * NI;     // i-tile (XCD-affine)
  const int jsplit = blockIdx.y;
  const int j0  = jsplit * NJ;

  ((float4*)sqjs)[tid] = ((const float4*)(sqn + j0))[tid];
  tls[tid] = CINF;

  // staging roles: w0,w1 -> A rows [0,64),[64,128); w2,w3 -> B likewise
  const ushort* gsrc = (w < 2) ? EA : EB;
  const int lrow  = L >> 2;                               // 0..15
  const int swz_k = ((L & 3) ^ ((L >> 3) & 3)) * 8;       // pre-swizzled k elems
  const int lds_woff = ((w < 2) ? 0 : 8192) + (w & 1) * 4096;
  // frag-read slot (same involution): slot = (L>>4) ^ (row bits[2:1])
  const int slot8 = (((L >> 4) ^ ((L >> 1) & 3)) * 8);

  const int myrow = tid >> 1;
  const int h     = tid & 1;
  const int gi    = i0 + myrow;

  float td[15]; int tj[15];
#pragma unroll
  for (int p = 0; p < 15; ++p) { td[p] = CINF; tj[p] = -1; }

  __syncthreads();

  for (int js = 0; js < NSUB; ++js) {
    const int jrow0 = j0 + js * JS;
    const int trowW = ((w < 2) ? i0 : jrow0) + (w & 1) * 64;
    const ushort* gbase = gsrc + (size_t)(trowW + lrow) * DIM + swz_k;

    // acc init = sqn_j along the r (reg) dim: one float4 per fj
    f32x4 acc[4][4];
#pragma unroll
    for (int fj = 0; fj < 4; ++fj) {
      const f32x4 sq = *(const f32x4*)&sqjs[js * 128 + wc * 64 + fj * 16 + (L >> 4) * 4];
#pragma unroll
      for (int fi = 0; fi < 4; ++fi) acc[fj][fi] = sq;
    }

    // prologue: stage chunk 0 into buf0 (4 loads/thread)
    {
      char* lp = sm + BUF0_OFF + lds_woff;
#pragma unroll
      for (int s = 0; s < 4; ++s)
        load_lds16(gbase + (size_t)(s * 16) * DIM, lp + s * 1024);
    }

#pragma unroll 2
    for (int ch = 0; ch < NCH; ++ch) {
      const int cb  = (ch & 1) ? BUF1_OFF : BUF0_OFF;
      const int nbo = (ch & 1) ? BUF0_OFF : BUF1_OFF;
      if (ch < NCH - 1) {
        char* lp = sm + nbo + lds_woff;
        const ushort* gp = gbase + (ch + 1) * BK;
#pragma unroll
        for (int s = 0; s < 4; ++s)
          load_lds16(gp + (size_t)(s * 16) * DIM, lp + s * 1024);
        // 4 just-issued loads may stay in flight; the 4 older (chunk ch)
        // must be complete.
        asm volatile("s_waitcnt vmcnt(4)" ::: "memory");
      } else {
        asm volatile("s_waitcnt vmcnt(0)" ::: "memory");
      }
      __builtin_amdgcn_s_barrier();          // stage(ch) visible to all
      __builtin_amdgcn_sched_barrier(0);

      const ushort* sA = (const ushort*)(sm + cb);          // [128][32]
      const ushort* sB = (const ushort*)(sm + cb + 8192);   // [128][32]

      short8 a[4], b[4];
#pragma unroll
      for (int f = 0; f < 4; ++f) {
        a[f] = *(const short8*)&sA[(wr * 64 + f * 16 + (L & 15)) * BK + slot8];
        b[f] = *(const short8*)&sB[(wc * 64 + f * 16 + (L & 15)) * BK + slot8];
      }
      // swapped operands: reg dim = j (b), lane dim = i (a)
#pragma unroll
      for (int fj = 0; fj < 4; ++fj)
#pragma unroll
        for (int fi = 0; fi < 4; ++fi)
          acc[fj][fi] = __builtin_amdgcn_mfma_f32_16x16x32_bf16(b[fj], a[fi], acc[fj][fi], 0, 0, 0);

      __builtin_amdgcn_sched_barrier(0);
      __builtin_amdgcn_s_barrier();          // reads of cb done before
                                             // next iter stages into it
    }

    // ---- writeback: pack r-pairs (consecutive j) to bf16, one b64/frag
#pragma unroll
    for (int fj = 0; fj < 4; ++fj)
#pragma unroll
      for (int fi = 0; fi < 4; ++fi) {
        const int i_t = wr * 64 + fi * 16 + (L & 15);
        const int jd  = wc * 32 + fj * 8 + (L >> 4) * 2;
        uint dw0, dw1;
        asm("v_cvt_pk_bf16_f32 %0, %1, %2" : "=v"(dw0) : "v"(acc[fj][fi][0]), "v"(acc[fj][fi][1]));
        asm("v_cvt_pk_bf16_f32 %0, %1, %2" : "=v"(dw1) : "v"(acc[fj][fi][2]), "v"(acc[fj][fi][3]));
        uint2 d2; d2.x = dw0; d2.y = dw1;
        *(uint2*)&sdp[i_t * SDW + jd] = d2;
      }
    __syncthreads();

    // ---- tau + self-poke + packed batch-8 scan over contiguous half-row
    const float tau = fminf(tls[myrow * 2], tls[myrow * 2 + 1]);
    const int selfc = gi - jrow0;
    if (selfc >= 0 && selfc < JS && h == (selfc >> 6))
      *(ushort*)(sm + myrow * (SDW * 4) + selfc * 2) = 0x7F80;   // bf16 +inf

    const uint* rowp = sdp + myrow * SDW + 32 * h;
    float guard = fminf(tau, td[14]);
    const int jb = jrow0 + 64 * h;
#pragma unroll 2
    for (int q = 0; q < 8; ++q) {
      const uint4 pv = *(const uint4*)&rowp[4 * q];
      float c8[8];
      c8[0] = __uint_as_float(pv.x << 16); c8[1] = __uint_as_float(pv.x & 0xffff0000u);
      c8[2] = __uint_as_float(pv.y << 16); c8[3] = __uint_as_float(pv.y & 0xffff0000u);
      c8[4] = __uint_as_float(pv.z << 16); c8[5] = __uint_as_float(pv.z & 0xffff0000u);
      c8[6] = __uint_as_float(pv.w << 16); c8[7] = __uint_as_float(pv.w & 0xffff0000u);
      const float m01 = fminf(c8[0], c8[1]), m23 = fminf(c8[2], c8[3]);
      const float m45 = fminf(c8[4], c8[5]), m67 = fminf(c8[6], c8[7]);
      const float mn = fminf(fminf(m01, m23), fminf(m45, m67));
      if (mn < guard) {
#pragma unroll
        for (int t = 0; t < 8; ++t) {
          const float dd = c8[t];
          if (dd < guard) {
            float cdv = dd; int cjv = jb + 8 * q + t;
#pragma unroll
            for (int p = 0; p < 15; ++p) {
              const bool lt = cdv < td[p];
              const float vmin = lt ? cdv : td[p];
              const float vmax = lt ? td[p] : cdv;
              const int imin = lt ? cjv : tj[p];
              const int imax = lt ? tj[p] : cjv;
              td[p] = vmin; tj[p] = imin; cdv = vmax; cjv = imax;
            }
            guard = fminf(tau, td[14]);
          }
        }
      }
    }
    tls[myrow * 2 + h] = td[14];
    __syncthreads();
  }

  // ---- pair-merge -> top-15 per (row, split); raw screen values out
  float* md  = (float*)sm;
  int*   mi_ = (int*)(sm + 16384);
#pragma unroll
  for (int p = 0; p < 15; ++p) {
    md[(myrow * 2 + h) * 15 + p]  = td[p];
    mi_[(myrow * 2 + h) * 15 + p] = tj[p];
  }
  __syncthreads();
  if (h == 0) {
    const float* da = &md[(myrow * 2 + 0) * 15];
    const float* db = &md[(myrow * 2 + 1) * 15];
    const int*   ia = &mi_[(myrow * 2 + 0) * 15];
    const int*   ib = &mi_[(myrow * 2 + 1) * 15];
    int pa = 0, pb = 0;
    const size_t base = ((size_t)gi * NJSPLIT + jsplit) * KNNK;
    for (int s2 = 0; s2 < KNNK; ++s2) {
      const float va = da[pa], vb = db[pb];
      float v; int ix;
      if (va <= vb) { v = va; ix = ia[pa]; ++pa; }
      else          { v = vb; ix = ib[pb]; ++pb; }
      cd[base + s2] = v;       // approx screen value; exact refine in sig
      ci[base + s2] = ix;
    }
  }
}

// ---------------------------------------------------------------- sig
// One wave per point. Merge 8 lists -> approx top-NCAND -> EXACT fp32
// refine -> exact top-15 -> curvature -> gram via split-bf16 MFMA ->
// shuffle bitonic-128 -> per-wave partial (no atomics).
__global__ __launch_bounds__(256) void sig_kernel(
    const float* __restrict__ E, const float* __restrict__ cd,
    const int* __restrict__ ci, const float* __restrict__ refc,
    const float* __restrict__ refa, float2* __restrict__ pacc) {
  __shared__ float gsm[4][292];   // per-wave: gram 16x17 (=272) + inv[16]

  const int tid = threadIdx.x;
  const int wid = tid >> 6;
  const int L   = tid & 63;
  const int i   = blockIdx.x * 4 + wid;

  // ---- merge 8 sorted 15-lists -> approx top-NCAND ids (lane c holds cand c)
  const size_t mbase = (size_t)i * (NJSPLIT * KNNK);
  float v0 = (L < 120)      ? cd[mbase + L]      : CINF;
  float v1 = (L + 64 < 120) ? cd[mbase + L + 64] : CINF;
  int   j0v = (L < 120)      ? ci[mbase + L]      : -1;
  int   j1v = (L + 64 < 120) ? ci[mbase + L + 64] : -1;
  int cand_nb = i;
  for (int sel = 0; sel < NCAND; ++sel) {
    float v; int idx, slot;
    if (v1 < v0) { v = v1; idx = j1v; slot = (L << 1) | 1; }
    else         { v = v0; idx = j0v; slot = (L << 1); }
#pragma unroll
    for (int off = 32; off > 0; off >>= 1) {
      const float ov = __shfl_down(v, off, 64);
      const int   oi = __shfl_down(idx, off, 64);
      const int   os = __shfl_down(slot, off, 64);
      if (ov < v) { v = ov; idx = oi; slot = os; }
    }
    const int imin = __shfl(idx, 0, 64);
    const int smin = __shfl(slot, 0, 64);
    if (L == sel) cand_nb = imin;
    if (L == (smin >> 1)) { if (smin & 1) v1 = CINF; else v0 = CINF; }
  }

  // ---- exact refine: fp32 squared distance for each candidate
  const float4* ei4 = (const float4*)(E + (size_t)i * DIM);
  const float4 e0 = ei4[2 * L];
  const float4 e1 = ei4[2 * L + 1];
  float csq = CINF;
#pragma unroll 2
  for (int c = 0; c < NCAND; ++c) {
    const int row = __shfl(cand_nb, c, 64);
    const float4* r4 = (const float4*)(E + (size_t)row * DIM);
    const float4 a0 = r4[2 * L];
    const float4 a1 = r4[2 * L + 1];
    const float d0 = a0.x - e0.x, d1 = a0.y - e0.y;
    const float d2 = a0.z - e0.z, d3 = a0.w - e0.w;
    const float d4 = a1.x - e1.x, d5 = a1.y - e1.y;
    const float d6 = a1.z - e1.z, d7 = a1.w - e1.w;
    float s8 = d0 * d0;
    s8 = fmaf(d1, d1, s8); s8 = fmaf(d2, d2, s8); s8 = fmaf(d3, d3, s8);
    s8 = fmaf(d4, d4, s8); s8 = fmaf(d5, d5, s8); s8 = fmaf(d6, d6, s8);
    s8 = fmaf(d7, d7, s8);
    const float sq = wave_sum_f(s8);
    if (L == c) csq = sq;
  }

  // ---- exact top-15 (ascending); lane-group (L&15)==sel captures rank sel
  float myd = 0.f; int mynb = i;
  for (int sel = 0; sel < KNNK; ++sel) {
    float v = csq; int who = L;
#pragma unroll
    for (int off = 32; off > 0; off >>= 1) {
      const float ov = __shfl_down(v, off, 64);
      const int   ow = __shfl_down(who, off, 64);
      if (ov < v) { v = ov; who = ow; }
    }
    const float vmin  = __shfl(v, 0, 64);
    const int   wmin  = __shfl(who, 0, 64);
    const int   nbmin = __shfl(cand_nb, wmin, 64);
    if ((L & 15) == sel) { myd = sqrtf(fmaxf(vmin, 1e-12f)); mynb = nbmin; }
    if (L == wmin) csq = CINF;
  }

  // ---- curvature (lanes 0..14 hold d_0..d_14)
  float curvs;
  {
    float dd = (L < KNNK) ? myd : 0.f;
    float tot = wave_sum_f(dd);
    float mean_d = tot / (float)KNNK + 1e-8f;
    float diff = (L < KNNK) ? (dd / mean_d - refc[i * KNNK + L]) : 0.f;
    curvs = wave_sum_f(diff * diff);
  }

  // ---- gram of raw neighbor differences (row = L&15; row 15 = self -> zero)
  const float4* nb4 = (const float4*)(E + (size_t)mynb * DIM);
  const int qo = (L >> 4) * 2;   // float4 index of this lane's 8-elem k-slice

  f32x4 gH, gX;
#pragma unroll
  for (int r = 0; r < 4; ++r) { gH[r] = 0.f; gX[r] = 0.f; }

#pragma unroll
  for (int c = 0; c < 16; ++c) {
    const float4 f0 = nb4[qo + c * 8];
    const float4 f1 = nb4[qo + 1 + c * 8];
    const float4 g0 = ei4[qo + c * 8];
    const float4 g1 = ei4[qo + 1 + c * 8];
    float v[8];
    v[0] = f0.x - g0.x; v[1] = f0.y - g0.y; v[2] = f0.z - g0.z; v[3] = f0.w - g0.w;
    v[4] = f1.x - g1.x; v[5] = f1.y - g1.y; v[6] = f1.z - g1.z; v[7] = f1.w - g1.w;
    short8 ah, al;
#pragma unroll
    for (int q = 0; q < 8; ++q) {
      short hh, ll;
      bf16split(v[q], hh, ll);
      ah[q] = hh; al[q] = ll;
    }
    gH = __builtin_amdgcn_mfma_f32_16x16x32_bf16(ah, ah, gH, 0, 0, 0);
    gX = __builtin_amdgcn_mfma_f32_16x16x32_bf16(ah, al, gX, 0, 0, 0);
    gX = __builtin_amdgcn_mfma_f32_16x16x32_bf16(al, ah, gX, 0, 0, 0);
  }

  // write gram to per-wave LDS: C/D layout col=L&15, row=(L>>4)*4+q
#pragma unroll
  for (int q = 0; q < 4; ++q)
    gsm[wid][((L >> 4) * 4 + q) * 17 + (L & 15)] = gH[q] + gX[q];
  asm volatile("s_waitcnt lgkmcnt(0)" ::: "memory");

  if (L < 16) {
    const float dv = gsm[wid][L * 17 + L];
    const float nrm = sqrtf(fmaxf(dv, 0.f));
    gsm[wid][272 + L] = 1.0f / fmaxf(nrm, 1e-8f);
  }
  asm volatile("s_waitcnt lgkmcnt(0)" ::: "memory");

  // cosines for pairs p = L and p+64
  float c0 = CINF, c1 = CINF;
#pragma unroll
  for (int s = 0; s < 2; ++s) {
    const int p = L + 64 * s;
    if (p < NPAIR) {
      int a = 0, rem = p, cnt = 14;
      while (rem >= cnt) { rem -= cnt; --cnt; ++a; }
      const int b = a + 1 + rem;
      const float cv = gsm[wid][a * 17 + b] * gsm[wid][272 + a] * gsm[wid][272 + b];
      if (s == 0) c0 = cv; else c1 = cv;
    }
  }

  // shuffle bitonic sort of 128 elems (2 per lane), ascending
#pragma unroll
  for (int k = 2; k <= 128; k <<= 1) {
#pragma unroll
    for (int j = k >> 1; j >= 1; j >>= 1) {
      const bool dir = ((L & (k >> 1)) == 0);
      if (j == 1) {
        const float lo = fminf(c0, c1), hi = fmaxf(c0, c1);
        c0 = dir ? lo : hi;
        c1 = dir ? hi : lo;
      } else {
        const int m = j >> 1;
        const float o0 = __shfl_xor(c0, m, 64);
        const float o1 = __shfl_xor(c1, m, 64);
        const bool lower = ((L & m) == 0);
        c0 = (lower == dir) ? fminf(c0, o0) : fmaxf(c0, o0);
        c1 = (lower == dir) ? fminf(c1, o1) : fmaxf(c1, o1);
      }
    }
  }

  // angular loss vs sorted reference (rank 2L, 2L+1)
  float part = 0.f;
  {
    const int r0 = 2 * L, r1 = 2 * L + 1;
    if (r0 < NPAIR) { const float dd = c0 - refa[(size_t)i * NPAIR + r0]; part += dd * dd; }
    if (r1 < NPAIR) { const float dd = c1 - refa[(size_t)i * NPAIR + r1]; part += dd * dd; }
  }
  part = wave_sum_f(part);
  if (L == 0) pacc[i] = make_float2(curvs, part);   // non-atomic per-wave slot
}

// ---------------------------------------------------------------- fin
__global__ __launch_bounds__(256) void fin_kernel(
    const float2* __restrict__ pacc, float* __restrict__ out) {
  __shared__ double redc[4], reda[4];
  const int tid = threadIdx.x;
  const int wid = tid >> 6;
  const int L   = tid & 63;
  double sc = 0.0, sa = 0.0;
#pragma unroll
  for (int q = 0; q < 32; ++q) {
    const float2 p = pacc[tid + 256 * q];
    sc += (double)p.x;
    sa += (double)p.y;
  }
#pragma unroll
  for (int m = 32; m > 0; m >>= 1) {
    sc += __shfl_xor(sc, m, 64);
    sa += __shfl_xor(sa, m, 64);
  }
  if (L == 0) { redc[wid] = sc; reda[wid] = sa; }
  __syncthreads();
  if (tid == 0) {
    const double curv = (redc[0] + redc[1] + redc[2] + redc[3]) /
                        ((double)NPTS * (double)KNNK);
    const double ang  = (reda[0] + reda[1] + reda[2] + reda[3]) /
                        ((double)NPTS * (double)NPAIR);
    out[0] = (float)(0.3 * curv + 0.7 * ang);
  }
}

// ---------------------------------------------------------------- launch
extern "C" void kernel_launch(void* const* d_in, const int* in_sizes, int n_in,
                              void* d_out, int out_size, void* d_ws,
                              size_t ws_size, hipStream_t stream) {
  const float* E    = (const float*)d_in[0];
  const float* refc = (const float*)d_in[1];
  const float* refa = (const float*)d_in[2];
  float* out = (float*)d_out;

  char* ws = (char*)d_ws;
  float*  sqn  = (float*)(ws + 1024);
  float2* pacc = (float2*)(ws + 65536);
  ushort* EA   = (ushort*)(ws + 1048576);
  ushort* EB   = (ushort*)(ws + 9437184);
  float*  cd   = (float*)(ws + 17825792);
  int*    ci   = (int*)(ws + 21757952);

  prep_kernel<<<NPTS / 4, 256, 0, stream>>>(E, sqn, EA, EB);
  knn_kernel<<<dim3(NPTS / NI, NJSPLIT), 256, 0, stream>>>(EA, EB, sqn, cd, ci);
  sig_kernel<<<NPTS / 4, 256, 0, stream>>>(E, cd, ci, refc, refa, pacc);
  fin_kernel<<<1, 256, 0, stream>>>(pacc, out);
}

// Round 6
// 378.484 us; speedup vs baseline: 1.2651x; 1.2651x over previous
//
#include <hip/hip_runtime.h>
#include <hip/hip_bf16.h>
#include <math.h>

#define NPTS  8192
#define DIM   512
#define KNNK  15
#define NCAND 22      // approx candidates kept for exact refine (bf16-screen safe margin)
#define NPAIR 105
#define CINF  3.0e38f

// knn tiling: 128 x 512 per block -> grid 64x16 = 1024 blocks = 4 blocks/CU
#define NI      128
#define NJSPLIT 16
#define NJ      (NPTS/NJSPLIT)   // 512
#define JS      128
#define NSUB    (NJ/JS)          // 4
#define BK      32
#define NCH     (DIM/BK)         // 16 chunks, double-buffered
#define SDW     68               // packed sdist row stride in dwords (64 data + 4 pad)

// knn LDS byte map (39936 B -> 4 blocks/CU):
//   staging buf0 [0,16384) buf1 [16384,32768)  (A[128][32] + B[128][32] bf16 each)
//   sdist packed bf16 [0,34816) aliases staging (disjoint lifetime)
#define BUF0_OFF   0
#define BUF1_OFF   16384
#define SQJ_OFF    34816
#define TLS_OFF    38912
#define KNN_LDS    39936

typedef __attribute__((ext_vector_type(8))) short short8;
typedef __attribute__((ext_vector_type(4))) float f32x4;

static __device__ __forceinline__ float wave_sum_f(float v) {
#pragma unroll
  for (int m = 32; m > 0; m >>= 1) v += __shfl_xor(v, m, 64);
  return v;
}

static __device__ __forceinline__ void load_lds16(const void* g, void* l) {
  __builtin_amdgcn_global_load_lds(
      (const __attribute__((address_space(1))) void*)g,
      (__attribute__((address_space(3))) void*)l, 16, 0, 0);
}

static __device__ __forceinline__ void bf16split(float x, short& h, short& l) {
  __hip_bfloat16 hb = __float2bfloat16(x);
  const float hf = __bfloat162float(hb);
  __hip_bfloat16 lb = __float2bfloat16(x - hf);
  h = *(short*)&hb;
  l = *(short*)&lb;
}

// ---------------------------------------------------------------- prep
// EA = bf16(-sqrt2 * E), EB = bf16(+sqrt2 * E): screen MFMA yields -2*dot
// directly so acc can be initialized with sqn_j (no writeback fma).
__global__ __launch_bounds__(256) void prep_kernel(
    const float* __restrict__ E, float* __restrict__ sqn,
    ushort* __restrict__ EA, ushort* __restrict__ EB) {
  const int row  = blockIdx.x * 4 + (threadIdx.x >> 6);
  const int lane = threadIdx.x & 63;
  const float SR2 = 1.4142135623730951f;
  float s = 0.f;
#pragma unroll
  for (int c = 0; c < 8; ++c) {
    const int d0 = lane + 64 * c;
    const float x = E[(size_t)row * DIM + d0];
    s = fmaf(x, x, s);
    __hip_bfloat16 ha = __float2bfloat16(-SR2 * x);
    __hip_bfloat16 hb = __float2bfloat16( SR2 * x);
    EA[(size_t)row * DIM + d0] = *(ushort*)&ha;
    EB[(size_t)row * DIM + d0] = *(ushort*)&hb;
  }
  s = wave_sum_f(s);
  if (lane == 0) sqn[row] = s;
}

// ---------------------------------------------------------------- knn
// bf16 screen, exact refine in sig. R6 = R2-verified kernel body with
// NJSPLIT=16 (grid 1024 blocks -> real 4 blocks/CU occupancy; per-wave
// chunk work unchanged) and bf16-ushort cd output (lossless: screen
// values are bf16-exact).
__global__ __launch_bounds__(256, 4) void knn_kernel(
    const ushort* __restrict__ EA, const ushort* __restrict__ EB,
    const float* __restrict__ sqn,
    ushort* __restrict__ cdu, int* __restrict__ ci) {
  __shared__ __align__(16) char sm[KNN_LDS];
  uint*  sdp  = (uint*)sm;                 // packed bf16-pair screen tile
  float* sqjs = (float*)(sm + SQJ_OFF);
  float* tls  = (float*)(sm + TLS_OFF);

  const int tid = threadIdx.x;
  const int w   = tid >> 6;
  const int L   = tid & 63;
  const int wr  = (w >> 1) & 1;        // i-half
  const int wc  = w & 1;               // j-half
  const int i0  = blockIdx.x * NI;     // i-tile (XCD-affine)
  const int jsplit = blockIdx.y;
  const int j0  = jsplit * NJ;

  if (tid < NJ / 4) ((float4*)sqjs)[tid] = ((const float4*)(sqn + j0))[tid];
  tls[tid] = CINF;

  // staging roles: w0,w1 -> A rows [0,64),[64,128); w2,w3 -> B likewise
  const ushort* gsrc = (w < 2) ? EA : EB;
  const int lrow  = L >> 2;                               // 0..15
  const int swz_k = ((L & 3) ^ ((L >> 3) & 3)) * 8;       // pre-swizzled k elems
  const int lds_woff = ((w < 2) ? 0 : 8192) + (w & 1) * 4096;
  // frag-read slot (same involution): slot = (L>>4) ^ (row bits[2:1])
  const int slot8 = (((L >> 4) ^ ((L >> 1) & 3)) * 8);

  const int myrow = tid >> 1;
  const int h     = tid & 1;
  const int gi    = i0 + myrow;

  float td[15]; int tj[15];
#pragma unroll
  for (int p = 0; p < 15; ++p) { td[p] = CINF; tj[p] = -1; }

  __syncthreads();

  for (int js = 0; js < NSUB; ++js) {
    const int jrow0 = j0 + js * JS;
    const int trowW = ((w < 2) ? i0 : jrow0) + (w & 1) * 64;
    const ushort* gbase = gsrc + (size_t)(trowW + lrow) * DIM + swz_k;

    // acc init = sqn_j along the r (reg) dim: one float4 per fj
    f32x4 acc[4][4];
#pragma unroll
    for (int fj = 0; fj < 4; ++fj) {
      const f32x4 sq = *(const f32x4*)&sqjs[js * 128 + wc * 64 + fj * 16 + (L >> 4) * 4];
#pragma unroll
      for (int fi = 0; fi < 4; ++fi) acc[fj][fi] = sq;
    }

    // prologue: stage chunk 0 into buf0
    {
      char* lp = sm + BUF0_OFF + lds_woff;
#pragma unroll
      for (int s = 0; s < 4; ++s)
        load_lds16(gbase + (size_t)(s * 16) * DIM, lp + s * 1024);
    }
    __syncthreads();

#pragma unroll 2
    for (int ch = 0; ch < NCH; ++ch) {
      const int cb  = (ch & 1) ? BUF1_OFF : BUF0_OFF;
      const int nbo = (ch & 1) ? BUF0_OFF : BUF1_OFF;
      if (ch < NCH - 1) {
        char* lp = sm + nbo + lds_woff;
        const ushort* gp = gbase + (ch + 1) * BK;
#pragma unroll
        for (int s = 0; s < 4; ++s)
          load_lds16(gp + (size_t)(s * 16) * DIM, lp + s * 1024);
      }

      const ushort* sA = (const ushort*)(sm + cb);          // [128][32]
      const ushort* sB = (const ushort*)(sm + cb + 8192);   // [128][32]

      short8 a[4], b[4];
#pragma unroll
      for (int f = 0; f < 4; ++f) {
        a[f] = *(const short8*)&sA[(wr * 64 + f * 16 + (L & 15)) * BK + slot8];
        b[f] = *(const short8*)&sB[(wc * 64 + f * 16 + (L & 15)) * BK + slot8];
      }
      // swapped operands: reg dim = j (b), lane dim = i (a)
#pragma unroll
      for (int fj = 0; fj < 4; ++fj)
#pragma unroll
        for (int fi = 0; fi < 4; ++fi)
          acc[fj][fi] = __builtin_amdgcn_mfma_f32_16x16x32_bf16(b[fj], a[fi], acc[fj][fi], 0, 0, 0);
      __syncthreads();   // drains next-chunk staging; orders buffer reuse
    }

    // ---- writeback: pack r-pairs (consecutive j) to bf16, one b64/frag
#pragma unroll
    for (int fj = 0; fj < 4; ++fj)
#pragma unroll
      for (int fi = 0; fi < 4; ++fi) {
        const int i_t = wr * 64 + fi * 16 + (L & 15);
        const int jd  = wc * 32 + fj * 8 + (L >> 4) * 2;
        uint dw0, dw1;
        asm("v_cvt_pk_bf16_f32 %0, %1, %2" : "=v"(dw0) : "v"(acc[fj][fi][0]), "v"(acc[fj][fi][1]));
        asm("v_cvt_pk_bf16_f32 %0, %1, %2" : "=v"(dw1) : "v"(acc[fj][fi][2]), "v"(acc[fj][fi][3]));
        uint2 d2; d2.x = dw0; d2.y = dw1;
        *(uint2*)&sdp[i_t * SDW + jd] = d2;
      }
    __syncthreads();

    // ---- tau + self-poke + packed batch-8 scan over contiguous half-row
    const float tau = fminf(tls[myrow * 2], tls[myrow * 2 + 1]);
    const int selfc = gi - jrow0;
    if (selfc >= 0 && selfc < JS && h == (selfc >> 6))
      *(ushort*)(sm + myrow * (SDW * 4) + selfc * 2) = 0x7F80;   // bf16 +inf

    const uint* rowp = sdp + myrow * SDW + 32 * h;
    float guard = fminf(tau, td[14]);
    const int jb = jrow0 + 64 * h;
#pragma unroll 2
    for (int q = 0; q < 8; ++q) {
      const uint4 pv = *(const uint4*)&rowp[4 * q];
      float c8[8];
      c8[0] = __uint_as_float(pv.x << 16); c8[1] = __uint_as_float(pv.x & 0xffff0000u);
      c8[2] = __uint_as_float(pv.y << 16); c8[3] = __uint_as_float(pv.y & 0xffff0000u);
      c8[4] = __uint_as_float(pv.z << 16); c8[5] = __uint_as_float(pv.z & 0xffff0000u);
      c8[6] = __uint_as_float(pv.w << 16); c8[7] = __uint_as_float(pv.w & 0xffff0000u);
      const float m01 = fminf(c8[0], c8[1]), m23 = fminf(c8[2], c8[3]);
      const float m45 = fminf(c8[4], c8[5]), m67 = fminf(c8[6], c8[7]);
      const float mn = fminf(fminf(m01, m23), fminf(m45, m67));
      if (mn < guard) {
#pragma unroll
        for (int t = 0; t < 8; ++t) {
          const float dd = c8[t];
          if (dd < guard) {
            float cdv = dd; int cjv = jb + 8 * q + t;
#pragma unroll
            for (int p = 0; p < 15; ++p) {
              const bool lt = cdv < td[p];
              const float vmin = lt ? cdv : td[p];
              const float vmax = lt ? td[p] : cdv;
              const int imin = lt ? cjv : tj[p];
              const int imax = lt ? tj[p] : cjv;
              td[p] = vmin; tj[p] = imin; cdv = vmax; cjv = imax;
            }
            guard = fminf(tau, td[14]);
          }
        }
      }
    }
    tls[myrow * 2 + h] = td[14];
    __syncthreads();
  }

  // ---- pair-merge -> top-15 per (row, split); bf16-ushort screen vals out
  float* md  = (float*)sm;
  int*   mi_ = (int*)(sm + 16384);
#pragma unroll
  for (int p = 0; p < 15; ++p) {
    md[(myrow * 2 + h) * 15 + p]  = td[p];
    mi_[(myrow * 2 + h) * 15 + p] = tj[p];
  }
  __syncthreads();
  if (h == 0) {
    const float* da = &md[(myrow * 2 + 0) * 15];
    const float* db = &md[(myrow * 2 + 1) * 15];
    const int*   ia = &mi_[(myrow * 2 + 0) * 15];
    const int*   ib = &mi_[(myrow * 2 + 1) * 15];
    int pa = 0, pb = 0;
    const size_t base = ((size_t)gi * NJSPLIT + jsplit) * KNNK;
    for (int s2 = 0; s2 < KNNK; ++s2) {
      const float va = da[pa], vb = db[pb];
      float v; int ix;
      if (va <= vb) { v = va; ix = ia[pa]; ++pa; }
      else          { v = vb; ix = ib[pb]; ++pb; }
      cdu[base + s2] = (ushort)(__float_as_uint(v) >> 16);  // bf16-exact
      ci[base + s2] = ix;
    }
  }
}

// ---------------------------------------------------------------- sig
// One wave per point. Merge 16 sorted 15-lists (240 cands, 4 regs/lane)
// -> approx top-NCAND -> EXACT fp32 refine -> exact top-15 -> curvature
// -> gram via split-bf16 MFMA -> shuffle bitonic-128 -> per-wave partial.
__global__ __launch_bounds__(256) void sig_kernel(
    const float* __restrict__ E, const ushort* __restrict__ cdu,
    const int* __restrict__ ci, const float* __restrict__ refc,
    const float* __restrict__ refa, float2* __restrict__ pacc) {
  __shared__ float gsm[4][292];   // per-wave: gram 16x17 (=272) + inv[16]

  const int tid = threadIdx.x;
  const int wid = tid >> 6;
  const int L   = tid & 63;
  const int i   = blockIdx.x * 4 + wid;

  // ---- merge 16 sorted 15-lists -> approx top-NCAND ids (lane c = cand c)
  const size_t mbase = (size_t)i * (NJSPLIT * KNNK);   // 240 per point
  float v0 = __uint_as_float((uint)cdu[mbase + L] << 16);
  float v1 = __uint_as_float((uint)cdu[mbase + L + 64] << 16);
  float v2 = __uint_as_float((uint)cdu[mbase + L + 128] << 16);
  float v3 = (L < 48) ? __uint_as_float((uint)cdu[mbase + L + 192] << 16) : CINF;
  int j0v = ci[mbase + L];
  int j1v = ci[mbase + L + 64];
  int j2v = ci[mbase + L + 128];
  int j3v = (L < 48) ? ci[mbase + L + 192] : -1;
  int cand_nb = i;
  for (int sel = 0; sel < NCAND; ++sel) {
    float v = v0; int idx = j0v; int which = 0;
    if (v1 < v) { v = v1; idx = j1v; which = 1; }
    if (v2 < v) { v = v2; idx = j2v; which = 2; }
    if (v3 < v) { v = v3; idx = j3v; which = 3; }
    int slot = (L << 2) | which;
#pragma unroll
    for (int off = 32; off > 0; off >>= 1) {
      const float ov = __shfl_down(v, off, 64);
      const int   oi = __shfl_down(idx, off, 64);
      const int   os = __shfl_down(slot, off, 64);
      if (ov < v) { v = ov; idx = oi; slot = os; }
    }
    const int imin = __shfl(idx, 0, 64);
    const int smin = __shfl(slot, 0, 64);
    if (L == sel) cand_nb = imin;
    if (L == (smin >> 2)) {
      const int wsel = smin & 3;
      if (wsel == 0) v0 = CINF;
      else if (wsel == 1) v1 = CINF;
      else if (wsel == 2) v2 = CINF;
      else v3 = CINF;
    }
  }

  // ---- exact refine: fp32 squared distance for each candidate
  const float4* ei4 = (const float4*)(E + (size_t)i * DIM);
  const float4 e0 = ei4[2 * L];
  const float4 e1 = ei4[2 * L + 1];
  float csq = CINF;
#pragma unroll 2
  for (int c = 0; c < NCAND; ++c) {
    const int row = __shfl(cand_nb, c, 64);
    const float4* r4 = (const float4*)(E + (size_t)row * DIM);
    const float4 a0 = r4[2 * L];
    const float4 a1 = r4[2 * L + 1];
    const float d0 = a0.x - e0.x, d1 = a0.y - e0.y;
    const float d2 = a0.z - e0.z, d3 = a0.w - e0.w;
    const float d4 = a1.x - e1.x, d5 = a1.y - e1.y;
    const float d6 = a1.z - e1.z, d7 = a1.w - e1.w;
    float s8 = d0 * d0;
    s8 = fmaf(d1, d1, s8); s8 = fmaf(d2, d2, s8); s8 = fmaf(d3, d3, s8);
    s8 = fmaf(d4, d4, s8); s8 = fmaf(d5, d5, s8); s8 = fmaf(d6, d6, s8);
    s8 = fmaf(d7, d7, s8);
    const float sq = wave_sum_f(s8);
    if (L == c) csq = sq;
  }

  // ---- exact top-15 (ascending); lane-group (L&15)==sel captures rank sel
  float myd = 0.f; int mynb = i;
  for (int sel = 0; sel < KNNK; ++sel) {
    float v = csq; int who = L;
#pragma unroll
    for (int off = 32; off > 0; off >>= 1) {
      const float ov = __shfl_down(v, off, 64);
      const int   ow = __shfl_down(who, off, 64);
      if (ov < v) { v = ov; who = ow; }
    }
    const float vmin  = __shfl(v, 0, 64);
    const int   wmin  = __shfl(who, 0, 64);
    const int   nbmin = __shfl(cand_nb, wmin, 64);
    if ((L & 15) == sel) { myd = sqrtf(fmaxf(vmin, 1e-12f)); mynb = nbmin; }
    if (L == wmin) csq = CINF;
  }

  // ---- curvature (lanes 0..14 hold d_0..d_14)
  float curvs;
  {
    float dd = (L < KNNK) ? myd : 0.f;
    float tot = wave_sum_f(dd);
    float mean_d = tot / (float)KNNK + 1e-8f;
    float diff = (L < KNNK) ? (dd / mean_d - refc[i * KNNK + L]) : 0.f;
    curvs = wave_sum_f(diff * diff);
  }

  // ---- gram of raw neighbor differences (row = L&15; row 15 = self -> zero)
  const float4* nb4 = (const float4*)(E + (size_t)mynb * DIM);
  const int qo = (L >> 4) * 2;   // float4 index of this lane's 8-elem k-slice

  f32x4 gH, gX;
#pragma unroll
  for (int r = 0; r < 4; ++r) { gH[r] = 0.f; gX[r] = 0.f; }

#pragma unroll
  for (int c = 0; c < 16; ++c) {
    const float4 f0 = nb4[qo + c * 8];
    const float4 f1 = nb4[qo + 1 + c * 8];
    const float4 g0 = ei4[qo + c * 8];
    const float4 g1 = ei4[qo + 1 + c * 8];
    float v[8];
    v[0] = f0.x - g0.x; v[1] = f0.y - g0.y; v[2] = f0.z - g0.z; v[3] = f0.w - g0.w;
    v[4] = f1.x - g1.x; v[5] = f1.y - g1.y; v[6] = f1.z - g1.z; v[7] = f1.w - g1.w;
    short8 ah, al;
#pragma unroll
    for (int q = 0; q < 8; ++q) {
      short hh, ll;
      bf16split(v[q], hh, ll);
      ah[q] = hh; al[q] = ll;
    }
    gH = __builtin_amdgcn_mfma_f32_16x16x32_bf16(ah, ah, gH, 0, 0, 0);
    gX = __builtin_amdgcn_mfma_f32_16x16x32_bf16(ah, al, gX, 0, 0, 0);
    gX = __builtin_amdgcn_mfma_f32_16x16x32_bf16(al, ah, gX, 0, 0, 0);
  }

  // write gram to per-wave LDS: C/D layout col=L&15, row=(L>>4)*4+q
#pragma unroll
  for (int q = 0; q < 4; ++q)
    gsm[wid][((L >> 4) * 4 + q) * 17 + (L & 15)] = gH[q] + gX[q];
  asm volatile("s_waitcnt lgkmcnt(0)" ::: "memory");

  if (L < 16) {
    const float dv = gsm[wid][L * 17 + L];
    const float nrm = sqrtf(fmaxf(dv, 0.f));
    gsm[wid][272 + L] = 1.0f / fmaxf(nrm, 1e-8f);
  }
  asm volatile("s_waitcnt lgkmcnt(0)" ::: "memory");

  // cosines for pairs p = L and p+64
  float c0 = CINF, c1 = CINF;
#pragma unroll
  for (int s = 0; s < 2; ++s) {
    const int p = L + 64 * s;
    if (p < NPAIR) {
      int a = 0, rem = p, cnt = 14;
      while (rem >= cnt) { rem -= cnt; --cnt; ++a; }
      const int b = a + 1 + rem;
      const float cv = gsm[wid][a * 17 + b] * gsm[wid][272 + a] * gsm[wid][272 + b];
      if (s == 0) c0 = cv; else c1 = cv;
    }
  }

  // shuffle bitonic sort of 128 elems (2 per lane), ascending
#pragma unroll
  for (int k = 2; k <= 128; k <<= 1) {
#pragma unroll
    for (int j = k >> 1; j >= 1; j >>= 1) {
      const bool dir = ((L & (k >> 1)) == 0);
      if (j == 1) {
        const float lo = fminf(c0, c1), hi = fmaxf(c0, c1);
        c0 = dir ? lo : hi;
        c1 = dir ? hi : lo;
      } else {
        const int m = j >> 1;
        const float o0 = __shfl_xor(c0, m, 64);
        const float o1 = __shfl_xor(c1, m, 64);
        const bool lower = ((L & m) == 0);
        c0 = (lower == dir) ? fminf(c0, o0) : fmaxf(c0, o0);
        c1 = (lower == dir) ? fminf(c1, o1) : fmaxf(c1, o1);
      }
    }
  }

  // angular loss vs sorted reference (rank 2L, 2L+1)
  float part = 0.f;
  {
    const int r0 = 2 * L, r1 = 2 * L + 1;
    if (r0 < NPAIR) { const float dd = c0 - refa[(size_t)i * NPAIR + r0]; part += dd * dd; }
    if (r1 < NPAIR) { const float dd = c1 - refa[(size_t)i * NPAIR + r1]; part += dd * dd; }
  }
  part = wave_sum_f(part);
  if (L == 0) pacc[i] = make_float2(curvs, part);   // non-atomic per-wave slot
}

// ---------------------------------------------------------------- fin
__global__ __launch_bounds__(256) void fin_kernel(
    const float2* __restrict__ pacc, float* __restrict__ out) {
  __shared__ double redc[4], reda[4];
  const int tid = threadIdx.x;
  const int wid = tid >> 6;
  const int L   = tid & 63;
  double sc = 0.0, sa = 0.0;
#pragma unroll
  for (int q = 0; q < 32; ++q) {
    const float2 p = pacc[tid + 256 * q];
    sc += (double)p.x;
    sa += (double)p.y;
  }
#pragma unroll
  for (int m = 32; m > 0; m >>= 1) {
    sc += __shfl_xor(sc, m, 64);
    sa += __shfl_xor(sa, m, 64);
  }
  if (L == 0) { redc[wid] = sc; reda[wid] = sa; }
  __syncthreads();
  if (tid == 0) {
    const double curv = (redc[0] + redc[1] + redc[2] + redc[3]) /
                        ((double)NPTS * (double)KNNK);
    const double ang  = (reda[0] + reda[1] + reda[2] + reda[3]) /
                        ((double)NPTS * (double)NPAIR);
    out[0] = (float)(0.3 * curv + 0.7 * ang);
  }
}

// ---------------------------------------------------------------- launch
extern "C" void kernel_launch(void* const* d_in, const int* in_sizes, int n_in,
                              void* d_out, int out_size, void* d_ws,
                              size_t ws_size, hipStream_t stream) {
  const float* E    = (const float*)d_in[0];
  const float* refc = (const float*)d_in[1];
  const float* refa = (const float*)d_in[2];
  float* out = (float*)d_out;

  char* ws = (char*)d_ws;
  float*  sqn  = (float*)(ws + 1024);
  float2* pacc = (float2*)(ws + 65536);
  ushort* EA   = (ushort*)(ws + 1048576);     //  8 MB
  ushort* EB   = (ushort*)(ws + 9437184);     //  8 MB
  ushort* cdu  = (ushort*)(ws + 17825792);    //  8192*16*15*2 = 3.93 MB
  int*    ci   = (int*)(ws + 21757952);       //  8192*16*15*4 = 7.86 MB

  prep_kernel<<<NPTS / 4, 256, 0, stream>>>(E, sqn, EA, EB);
  knn_kernel<<<dim3(NPTS / NI, NJSPLIT), 256, 0, stream>>>(EA, EB, sqn, cdu, ci);
  sig_kernel<<<NPTS / 4, 256, 0, stream>>>(E, cdu, ci, refc, refa, pacc);
  fin_kernel<<<1, 256, 0, stream>>>(pacc, out);
}

// Round 7
// 340.985 us; speedup vs baseline: 1.4043x; 1.1100x over previous
//
#include <hip/hip_runtime.h>
#include <hip/hip_bf16.h>
#include <math.h>

#define NPTS  8192
#define DIM   512
#define KNNK  15
#define NCAND 22
#define NPAIR 105
#define CINF  3.0e38f
#define EMPTYK 0xFFFFFFFFu
#define TAU_MARGIN (3u << 16)   // +3 bf16 ulp on the screen threshold

// knn tiling (R2-verified geometry): 128 x 512 per block
#define NI      128
#define NJSPLIT 16
#define NJ      (NPTS/NJSPLIT)   // 512
#define JS      128
#define NSUB    (NJ/JS)          // 4
#define BK      32
#define NCH     (DIM/BK)         // 16 chunks, double-buffered
#define SDW     68               // packed sdist row stride in dwords
#define NPSPL   2                // probe splits (phase 1)

// knn LDS byte map (39936 B -> 4 blocks/CU):
//   staging buf0 [0,16384) buf1 [16384,32768); sdist bf16 [0,34816) aliased
#define BUF0_OFF   0
#define BUF1_OFF   16384
#define SQJ_OFF    34816
#define TLS_OFF    38912
#define KNN_LDS    39936

typedef __attribute__((ext_vector_type(8))) short short8;
typedef __attribute__((ext_vector_type(4))) float f32x4;
typedef unsigned int uint32;

static __device__ __forceinline__ float wave_sum_f(float v) {
#pragma unroll
  for (int m = 32; m > 0; m >>= 1) v += __shfl_xor(v, m, 64);
  return v;
}

static __device__ __forceinline__ void load_lds16(const void* g, void* l) {
  __builtin_amdgcn_global_load_lds(
      (const __attribute__((address_space(1))) void*)g,
      (__attribute__((address_space(3))) void*)l, 16, 0, 0);
}

static __device__ __forceinline__ void bf16split(float x, short& h, short& l) {
  __hip_bfloat16 hb = __float2bfloat16(x);
  const float hf = __bfloat162float(hb);
  __hip_bfloat16 lb = __float2bfloat16(x - hf);
  h = *(short*)&hb;
  l = *(short*)&lb;
}

// sorted-ascending insert of key c into td[0..14]: 15x(min_u32+max_u32)
static __device__ __forceinline__ void chain15(uint32 (&td)[15], uint32 c) {
#pragma unroll
  for (int p = 0; p < 15; ++p) {
    const uint32 lo = min(c, td[p]);
    const uint32 hi = max(c, td[p]);
    td[p] = lo; c = hi;
  }
}

// ---------------------------------------------------------------- prep
__global__ __launch_bounds__(256) void prep_kernel(
    const float* __restrict__ E, float* __restrict__ sqn,
    ushort* __restrict__ EA, ushort* __restrict__ EB) {
  const int row  = blockIdx.x * 4 + (threadIdx.x >> 6);
  const int lane = threadIdx.x & 63;
  const float SR2 = 1.4142135623730951f;
  float s = 0.f;
#pragma unroll
  for (int c = 0; c < 8; ++c) {
    const int d0 = lane + 64 * c;
    const float x = E[(size_t)row * DIM + d0];
    s = fmaf(x, x, s);
    __hip_bfloat16 ha = __float2bfloat16(-SR2 * x);
    __hip_bfloat16 hb = __float2bfloat16( SR2 * x);
    EA[(size_t)row * DIM + d0] = *(ushort*)&ha;
    EB[(size_t)row * DIM + d0] = *(ushort*)&hb;
  }
  s = wave_sum_f(s);
  if (lane == 0) sqn[row] = s;
}

// ---------------------------------------------------------------- knn
// PHASE 1 (splits 0..1): unconditional per-split top-15 (key domain) +
//   writes tau_s = per-row 15th key.
// PHASE 2 (splits 2..15): guard = min(tau_0,tau_1)+margin (provable upper
//   bound on global 15th + screen-error margin); only admitted keys are
//   chained. Batched push(12 static reg slots)/drain kills the wave-any
//   chain amplification that made R6 VALU-bound.
#define PUSHK(k_) { const uint32 kv_ = (k_); \
  p0=(nc==0)?kv_:p0;  p1=(nc==1)?kv_:p1;  p2=(nc==2)?kv_:p2; \
  p3=(nc==3)?kv_:p3;  p4=(nc==4)?kv_:p4;  p5=(nc==5)?kv_:p5; \
  p6=(nc==6)?kv_:p6;  p7=(nc==7)?kv_:p7;  p8=(nc==8)?kv_:p8; \
  p9=(nc==9)?kv_:p9;  p10=(nc==10)?kv_:p10; p11=(nc==11)?kv_:p11; \
  ++nc; }

#define DRAINALL { \
  if (__any(nc >  0)) { if (nc >  0) chain15(td, p0);  } \
  if (__any(nc >  1)) { if (nc >  1) chain15(td, p1);  } \
  if (__any(nc >  2)) { if (nc >  2) chain15(td, p2);  } \
  if (__any(nc >  3)) { if (nc >  3) chain15(td, p3);  } \
  if (__any(nc >  4)) { if (nc >  4) chain15(td, p4);  } \
  if (__any(nc >  5)) { if (nc >  5) chain15(td, p5);  } \
  if (__any(nc >  6)) { if (nc >  6) chain15(td, p6);  } \
  if (__any(nc >  7)) { if (nc >  7) chain15(td, p7);  } \
  if (__any(nc >  8)) { if (nc >  8) chain15(td, p8);  } \
  if (__any(nc >  9)) { if (nc >  9) chain15(td, p9);  } \
  if (__any(nc > 10)) { if (nc > 10) chain15(td, p10); } \
  if (__any(nc > 11)) { if (nc > 11) chain15(td, p11); } \
  nc = 0; guard = min(tau_cur, td[14]); }

template <int PHASE>
__global__ __launch_bounds__(256, 4) void knn_kernel(
    const ushort* __restrict__ EA, const ushort* __restrict__ EB,
    const float* __restrict__ sqn,
    uint32* __restrict__ knnk, uint32* __restrict__ tauk) {
  __shared__ __align__(16) char sm[KNN_LDS];
  uint32* sdp  = (uint32*)sm;                 // packed bf16-pair screen tile
  float*  sqjs = (float*)(sm + SQJ_OFF);
  uint32* tlsu = (uint32*)(sm + TLS_OFF);

  const int tid = threadIdx.x;
  const int w   = tid >> 6;
  const int L   = tid & 63;
  const int wr  = (w >> 1) & 1;        // i-half
  const int wc  = w & 1;               // j-half
  const int i0  = blockIdx.x * NI;     // i-tile (XCD-affine)
  const int jsplit = (PHASE == 1) ? blockIdx.y : (blockIdx.y + NPSPL);
  const int j0  = jsplit * NJ;

  if (tid < NJ / 4) ((float4*)sqjs)[tid] = ((const float4*)(sqn + j0))[tid];
  tlsu[tid] = EMPTYK;

  // staging roles: w0,w1 -> A rows [0,64),[64,128); w2,w3 -> B likewise
  const ushort* gsrc = (w < 2) ? EA : EB;
  const int lrow  = L >> 2;
  const int swz_k = ((L & 3) ^ ((L >> 3) & 3)) * 8;       // pre-swizzled k
  const int lds_woff = ((w < 2) ? 0 : 8192) + (w & 1) * 4096;
  const int slot8 = (((L >> 4) ^ ((L >> 1) & 3)) * 8);    // same involution

  const int myrow = tid >> 1;
  const int h     = tid & 1;
  const int gi    = i0 + myrow;

  uint32 tauA = EMPTYK;
  if (PHASE == 2) {
    const uint32 t0 = tauk[gi];
    const uint32 t1 = tauk[NPTS + gi];
    tauA = min(t0, t1) + TAU_MARGIN;
  }

  uint32 td[15];
#pragma unroll
  for (int p = 0; p < 15; ++p) td[p] = EMPTYK;

  __syncthreads();

  for (int js = 0; js < NSUB; ++js) {
    const int jrow0 = j0 + js * JS;
    const int trowW = ((w < 2) ? i0 : jrow0) + (w & 1) * 64;
    const ushort* gbase = gsrc + (size_t)(trowW + lrow) * DIM + swz_k;

    // acc init = sqn_j along the r (reg) dim
    f32x4 acc[4][4];
#pragma unroll
    for (int fj = 0; fj < 4; ++fj) {
      const f32x4 sq = *(const f32x4*)&sqjs[js * 128 + wc * 64 + fj * 16 + (L >> 4) * 4];
#pragma unroll
      for (int fi = 0; fi < 4; ++fi) acc[fj][fi] = sq;
    }

    // prologue: stage chunk 0 into buf0
    {
      char* lp = sm + BUF0_OFF + lds_woff;
#pragma unroll
      for (int s = 0; s < 4; ++s)
        load_lds16(gbase + (size_t)(s * 16) * DIM, lp + s * 1024);
    }
    __syncthreads();

#pragma unroll 2
    for (int ch = 0; ch < NCH; ++ch) {
      const int cb  = (ch & 1) ? BUF1_OFF : BUF0_OFF;
      const int nbo = (ch & 1) ? BUF0_OFF : BUF1_OFF;
      if (ch < NCH - 1) {
        char* lp = sm + nbo + lds_woff;
        const ushort* gp = gbase + (ch + 1) * BK;
#pragma unroll
        for (int s = 0; s < 4; ++s)
          load_lds16(gp + (size_t)(s * 16) * DIM, lp + s * 1024);
      }

      const ushort* sA = (const ushort*)(sm + cb);          // [128][32]
      const ushort* sB = (const ushort*)(sm + cb + 8192);   // [128][32]

      short8 a[4], b[4];
#pragma unroll
      for (int f = 0; f < 4; ++f) {
        a[f] = *(const short8*)&sA[(wr * 64 + f * 16 + (L & 15)) * BK + slot8];
        b[f] = *(const short8*)&sB[(wc * 64 + f * 16 + (L & 15)) * BK + slot8];
      }
#pragma unroll
      for (int fj = 0; fj < 4; ++fj)
#pragma unroll
        for (int fi = 0; fi < 4; ++fi)
          acc[fj][fi] = __builtin_amdgcn_mfma_f32_16x16x32_bf16(b[fj], a[fi], acc[fj][fi], 0, 0, 0);
      __syncthreads();
    }

    // ---- writeback: pack r-pairs (consecutive j) to bf16, one b64/frag
#pragma unroll
    for (int fj = 0; fj < 4; ++fj)
#pragma unroll
      for (int fi = 0; fi < 4; ++fi) {
        const int i_t = wr * 64 + fi * 16 + (L & 15);
        const int jd  = wc * 32 + fj * 8 + (L >> 4) * 2;
        uint32 dw0, dw1;
        asm("v_cvt_pk_bf16_f32 %0, %1, %2" : "=v"(dw0) : "v"(acc[fj][fi][0]), "v"(acc[fj][fi][1]));
        asm("v_cvt_pk_bf16_f32 %0, %1, %2" : "=v"(dw1) : "v"(acc[fj][fi][2]), "v"(acc[fj][fi][3]));
        uint2 d2; d2.x = dw0; d2.y = dw1;
        *(uint2*)&sdp[i_t * SDW + jd] = d2;
      }
    __syncthreads();

    // ---- self-poke + key scan with batched drains
    uint32 tau_cur = (PHASE == 1)
        ? min(tlsu[myrow * 2], tlsu[myrow * 2 + 1])
        : tauA;
    const int selfc = gi - jrow0;
    if (selfc >= 0 && selfc < JS && h == (selfc >> 6))
      *(ushort*)(sm + myrow * (SDW * 4) + selfc * 2) = 0x7F80;   // bf16 +inf

    const uint32* rowp = sdp + myrow * SDW + 32 * h;
    const uint32 jb = (uint32)(jrow0 + 64 * h);   // low 6 bits free
    uint32 guard = min(tau_cur, td[14]);
    uint32 nc = 0;
    uint32 p0=0,p1=0,p2=0,p3=0,p4=0,p5=0,p6=0,p7=0,p8=0,p9=0,p10=0,p11=0;

#pragma unroll 2
    for (int q = 0; q < 8; ++q) {
      const uint4 pv = *(const uint4*)&rowp[4 * q];
      const uint32 jq = jb + 8 * q;
      uint32 kx;
      kx = (pv.x << 16)          | (jq + 0); if (kx < guard) PUSHK(kx);
      kx = (pv.x & 0xFFFF0000u)  | (jq + 1); if (kx < guard) PUSHK(kx);
      kx = (pv.y << 16)          | (jq + 2); if (kx < guard) PUSHK(kx);
      kx = (pv.y & 0xFFFF0000u)  | (jq + 3); if (kx < guard) PUSHK(kx);
      kx = (pv.z << 16)          | (jq + 4); if (kx < guard) PUSHK(kx);
      kx = (pv.z & 0xFFFF0000u)  | (jq + 5); if (kx < guard) PUSHK(kx);
      kx = (pv.w << 16)          | (jq + 6); if (kx < guard) PUSHK(kx);
      kx = (pv.w & 0xFFFF0000u)  | (jq + 7); if (kx < guard) PUSHK(kx);
      if (__any(nc >= 4)) { DRAINALL; }   // cap: 3 carried + 8/q <= 11 < 12
    }
    if (__any(nc > 0)) { DRAINALL; }

    if (PHASE == 1) tlsu[myrow * 2 + h] = td[14];
    __syncthreads();
  }

  // ---- pair-merge (key domain) -> top-15 per (row, split)
  uint32* mdk = (uint32*)sm;   // [256][15]
#pragma unroll
  for (int p = 0; p < 15; ++p) mdk[(myrow * 2 + h) * 15 + p] = td[p];
  __syncthreads();
  if (h == 0) {
    const uint32* la = &mdk[(myrow * 2 + 0) * 15];
    const uint32* lb = &mdk[(myrow * 2 + 1) * 15];
    int pa = 0, pb = 0;
    const size_t base = ((size_t)gi * NJSPLIT + jsplit) * KNNK;
    uint32 last = EMPTYK;
    for (int s = 0; s < KNNK; ++s) {
      const uint32 va = la[pa], vb = lb[pb];
      uint32 v;
      if (va <= vb) { v = va; ++pa; } else { v = vb; ++pb; }
      knnk[base + s] = v;
      last = v;
    }
    if (PHASE == 1) tauk[jsplit * NPTS + gi] = last;   // 15th key of split
  }
}

// ---------------------------------------------------------------- sig
// Merge 240 keys (16 lists) -> approx top-NCAND -> EXACT fp32 refine ->
// exact top-15 -> curvature -> gram -> bitonic-128 -> per-wave partial.
__global__ __launch_bounds__(256) void sig_kernel(
    const float* __restrict__ E, const uint32* __restrict__ knnk,
    const float* __restrict__ refc, const float* __restrict__ refa,
    float2* __restrict__ pacc) {
  __shared__ float gsm[4][292];

  const int tid = threadIdx.x;
  const int wid = tid >> 6;
  const int L   = tid & 63;
  const int i   = blockIdx.x * 4 + wid;

  // ---- merge: lane c of first NCAND lanes captures candidate key c
  const uint32* kl = knnk + (size_t)i * (NJSPLIT * KNNK);   // 240 keys
  uint32 k0 = kl[L];
  uint32 k1 = kl[L + 64];
  uint32 k2 = kl[L + 128];
  uint32 k3 = (L < 48) ? kl[L + 192] : EMPTYK;
  uint32 cand_key = EMPTYK;
  for (int sel = 0; sel < NCAND; ++sel) {
    uint32 v = k0; int which = 0;
    if (k1 < v) { v = k1; which = 1; }
    if (k2 < v) { v = k2; which = 2; }
    if (k3 < v) { v = k3; which = 3; }
    int slot = (L << 2) | which;
#pragma unroll
    for (int off = 32; off > 0; off >>= 1) {
      const uint32 ov = (uint32)__shfl_down((int)v, off, 64);
      const int    os = __shfl_down(slot, off, 64);
      if (ov < v) { v = ov; slot = os; }
    }
    const uint32 vmin = (uint32)__shfl((int)v, 0, 64);
    const int    smin = __shfl(slot, 0, 64);
    if (L == sel) cand_key = vmin;
    if (L == (smin >> 2)) {
      const int wsel = smin & 3;
      if (wsel == 0) k0 = EMPTYK;
      else if (wsel == 1) k1 = EMPTYK;
      else if (wsel == 2) k2 = EMPTYK;
      else k3 = EMPTYK;
    }
  }
  // decode: j in low 13 bits; invalid (empty/inf) -> self sentinel
  int cand_nb = ((cand_key >> 16) < 0x7F80u) ? (int)(cand_key & 0x1FFFu) : i;

  // ---- exact refine: fp32 squared distance for each candidate
  const float4* ei4 = (const float4*)(E + (size_t)i * DIM);
  const float4 e0 = ei4[2 * L];
  const float4 e1 = ei4[2 * L + 1];
  float csq = CINF;
#pragma unroll 2
  for (int c = 0; c < NCAND; ++c) {
    const int row = __shfl(cand_nb, c, 64);
    const float4* r4 = (const float4*)(E + (size_t)row * DIM);
    const float4 a0 = r4[2 * L];
    const float4 a1 = r4[2 * L + 1];
    const float d0 = a0.x - e0.x, d1 = a0.y - e0.y;
    const float d2 = a0.z - e0.z, d3 = a0.w - e0.w;
    const float d4 = a1.x - e1.x, d5 = a1.y - e1.y;
    const float d6 = a1.z - e1.z, d7 = a1.w - e1.w;
    float s8 = d0 * d0;
    s8 = fmaf(d1, d1, s8); s8 = fmaf(d2, d2, s8); s8 = fmaf(d3, d3, s8);
    s8 = fmaf(d4, d4, s8); s8 = fmaf(d5, d5, s8); s8 = fmaf(d6, d6, s8);
    s8 = fmaf(d7, d7, s8);
    const float sq = wave_sum_f(s8);
    if (L == c) csq = (row == i) ? CINF : sq;   // self sentinel = invalid
  }

  // ---- exact top-15 (ascending)
  float myd = 0.f; int mynb = i;
  for (int sel = 0; sel < KNNK; ++sel) {
    float v = csq; int who = L;
#pragma unroll
    for (int off = 32; off > 0; off >>= 1) {
      const float ov = __shfl_down(v, off, 64);
      const int   ow = __shfl_down(who, off, 64);
      if (ov < v) { v = ov; who = ow; }
    }
    const float vmin  = __shfl(v, 0, 64);
    const int   wmin  = __shfl(who, 0, 64);
    const int   nbmin = __shfl(cand_nb, wmin, 64);
    if ((L & 15) == sel) { myd = sqrtf(fmaxf(vmin, 1e-12f)); mynb = nbmin; }
    if (L == wmin) csq = CINF;
  }

  // ---- curvature
  float curvs;
  {
    float dd = (L < KNNK) ? myd : 0.f;
    float tot = wave_sum_f(dd);
    float mean_d = tot / (float)KNNK + 1e-8f;
    float diff = (L < KNNK) ? (dd / mean_d - refc[i * KNNK + L]) : 0.f;
    curvs = wave_sum_f(diff * diff);
  }

  // ---- gram of raw neighbor differences
  const float4* nb4 = (const float4*)(E + (size_t)mynb * DIM);
  const int qo = (L >> 4) * 2;

  f32x4 gH, gX;
#pragma unroll
  for (int r = 0; r < 4; ++r) { gH[r] = 0.f; gX[r] = 0.f; }

#pragma unroll
  for (int c = 0; c < 16; ++c) {
    const float4 f0 = nb4[qo + c * 8];
    const float4 f1 = nb4[qo + 1 + c * 8];
    const float4 g0 = ei4[qo + c * 8];
    const float4 g1 = ei4[qo + 1 + c * 8];
    float v[8];
    v[0] = f0.x - g0.x; v[1] = f0.y - g0.y; v[2] = f0.z - g0.z; v[3] = f0.w - g0.w;
    v[4] = f1.x - g1.x; v[5] = f1.y - g1.y; v[6] = f1.z - g1.z; v[7] = f1.w - g1.w;
    short8 ah, al;
#pragma unroll
    for (int q = 0; q < 8; ++q) {
      short hh, ll;
      bf16split(v[q], hh, ll);
      ah[q] = hh; al[q] = ll;
    }
    gH = __builtin_amdgcn_mfma_f32_16x16x32_bf16(ah, ah, gH, 0, 0, 0);
    gX = __builtin_amdgcn_mfma_f32_16x16x32_bf16(ah, al, gX, 0, 0, 0);
    gX = __builtin_amdgcn_mfma_f32_16x16x32_bf16(al, ah, gX, 0, 0, 0);
  }

#pragma unroll
  for (int q = 0; q < 4; ++q)
    gsm[wid][((L >> 4) * 4 + q) * 17 + (L & 15)] = gH[q] + gX[q];
  asm volatile("s_waitcnt lgkmcnt(0)" ::: "memory");

  if (L < 16) {
    const float dv = gsm[wid][L * 17 + L];
    const float nrm = sqrtf(fmaxf(dv, 0.f));
    gsm[wid][272 + L] = 1.0f / fmaxf(nrm, 1e-8f);
  }
  asm volatile("s_waitcnt lgkmcnt(0)" ::: "memory");

  float c0 = CINF, c1 = CINF;
#pragma unroll
  for (int s = 0; s < 2; ++s) {
    const int p = L + 64 * s;
    if (p < NPAIR) {
      int a = 0, rem = p, cnt = 14;
      while (rem >= cnt) { rem -= cnt; --cnt; ++a; }
      const int b = a + 1 + rem;
      const float cv = gsm[wid][a * 17 + b] * gsm[wid][272 + a] * gsm[wid][272 + b];
      if (s == 0) c0 = cv; else c1 = cv;
    }
  }

  // bitonic-128 ascending
#pragma unroll
  for (int k = 2; k <= 128; k <<= 1) {
#pragma unroll
    for (int j = k >> 1; j >= 1; j >>= 1) {
      const bool dir = ((L & (k >> 1)) == 0);
      if (j == 1) {
        const float lo = fminf(c0, c1), hi = fmaxf(c0, c1);
        c0 = dir ? lo : hi;
        c1 = dir ? hi : lo;
      } else {
        const int m = j >> 1;
        const float o0 = __shfl_xor(c0, m, 64);
        const float o1 = __shfl_xor(c1, m, 64);
        const bool lower = ((L & m) == 0);
        c0 = (lower == dir) ? fminf(c0, o0) : fmaxf(c0, o0);
        c1 = (lower == dir) ? fminf(c1, o1) : fmaxf(c1, o1);
      }
    }
  }

  float part = 0.f;
  {
    const int r0 = 2 * L, r1 = 2 * L + 1;
    if (r0 < NPAIR) { const float dd = c0 - refa[(size_t)i * NPAIR + r0]; part += dd * dd; }
    if (r1 < NPAIR) { const float dd = c1 - refa[(size_t)i * NPAIR + r1]; part += dd * dd; }
  }
  part = wave_sum_f(part);
  if (L == 0) pacc[i] = make_float2(curvs, part);
}

// ---------------------------------------------------------------- fin
__global__ __launch_bounds__(256) void fin_kernel(
    const float2* __restrict__ pacc, float* __restrict__ out) {
  __shared__ double redc[4], reda[4];
  const int tid = threadIdx.x;
  const int wid = tid >> 6;
  const int L   = tid & 63;
  double sc = 0.0, sa = 0.0;
#pragma unroll
  for (int q = 0; q < 32; ++q) {
    const float2 p = pacc[tid + 256 * q];
    sc += (double)p.x;
    sa += (double)p.y;
  }
#pragma unroll
  for (int m = 32; m > 0; m >>= 1) {
    sc += __shfl_xor(sc, m, 64);
    sa += __shfl_xor(sa, m, 64);
  }
  if (L == 0) { redc[wid] = sc; reda[wid] = sa; }
  __syncthreads();
  if (tid == 0) {
    const double curv = (redc[0] + redc[1] + redc[2] + redc[3]) /
                        ((double)NPTS * (double)KNNK);
    const double ang  = (reda[0] + reda[1] + reda[2] + reda[3]) /
                        ((double)NPTS * (double)NPAIR);
    out[0] = (float)(0.3 * curv + 0.7 * ang);
  }
}

// ---------------------------------------------------------------- launch
extern "C" void kernel_launch(void* const* d_in, const int* in_sizes, int n_in,
                              void* d_out, int out_size, void* d_ws,
                              size_t ws_size, hipStream_t stream) {
  const float* E    = (const float*)d_in[0];
  const float* refc = (const float*)d_in[1];
  const float* refa = (const float*)d_in[2];
  float* out = (float*)d_out;

  char* ws = (char*)d_ws;
  float*  sqn  = (float*)(ws + 1024);
  float2* pacc = (float2*)(ws + 65536);
  uint32* tauk = (uint32*)(ws + 131072);      // [2][NPTS] phase-1 taus
  ushort* EA   = (ushort*)(ws + 1048576);
  ushort* EB   = (ushort*)(ws + 9437184);
  uint32* knnk = (uint32*)(ws + 17825792);    // [NPTS][16][15] keys

  prep_kernel<<<NPTS / 4, 256, 0, stream>>>(E, sqn, EA, EB);
  knn_kernel<1><<<dim3(NPTS / NI, NPSPL), 256, 0, stream>>>(EA, EB, sqn, knnk, tauk);
  knn_kernel<2><<<dim3(NPTS / NI, NJSPLIT - NPSPL), 256, 0, stream>>>(EA, EB, sqn, knnk, tauk);
  sig_kernel<<<NPTS / 4, 256, 0, stream>>>(E, knnk, refc, refa, pacc);
  fin_kernel<<<1, 256, 0, stream>>>(pacc, out);
}

// Round 8
// 313.115 us; speedup vs baseline: 1.5293x; 1.0890x over previous
//
#include <hip/hip_runtime.h>
#include <hip/hip_bf16.h>
#include <math.h>

#define NPTS  8192
#define DIM   512
#define KNNK  15
#define NCAND 22
#define NPAIR 105
#define CINF  3.0e38f
#define EMPTYK 0xFFFFFFFFu
#define TAU_MARGIN (3u << 16)   // +3 bf16 ulp on the screen threshold

// knn tiling
#define NI      128
#define NJSPLIT 16
#define NJ      (NPTS/NJSPLIT)   // 512
#define JS      128
#define NSUB    (NJ/JS)          // 4
#define BK      32
#define NCH     (DIM/BK)         // 16 chunks, double-buffered
#define SDW     68               // packed sdist row stride in dwords
#define NPROBE  8                // probe subtiles (j < 1024 = splits 0..1)
#define NLIST   (NPROBE + NJSPLIT - 2)   // 22 lists per point
#define NKEYS   (NLIST * KNNK)           // 330 keys per point

// knn LDS byte map (39936 B -> 4 blocks/CU):
//   staging buf0 [0,16384) buf1 [16384,32768); sdist bf16 [0,34816) aliased
#define BUF0_OFF   0
#define BUF1_OFF   16384
#define SQJ_OFF    34816
#define KNN_LDS    39936

typedef __attribute__((ext_vector_type(8))) short short8;
typedef __attribute__((ext_vector_type(4))) float f32x4;
typedef unsigned int uint32;

static __device__ __forceinline__ float wave_sum_f(float v) {
#pragma unroll
  for (int m = 32; m > 0; m >>= 1) v += __shfl_xor(v, m, 64);
  return v;
}

static __device__ __forceinline__ void load_lds16(const void* g, void* l) {
  __builtin_amdgcn_global_load_lds(
      (const __attribute__((address_space(1))) void*)g,
      (__attribute__((address_space(3))) void*)l, 16, 0, 0);
}

static __device__ __forceinline__ void bf16split(float x, short& h, short& l) {
  __hip_bfloat16 hb = __float2bfloat16(x);
  const float hf = __bfloat162float(hb);
  __hip_bfloat16 lb = __float2bfloat16(x - hf);
  h = *(short*)&hb;
  l = *(short*)&lb;
}

// sorted-ascending insert of key c into td[0..14]
static __device__ __forceinline__ void chain15(uint32 (&td)[15], uint32 c) {
#pragma unroll
  for (int p = 0; p < 15; ++p) {
    const uint32 lo = min(c, td[p]);
    const uint32 hi = max(c, td[p]);
    td[p] = lo; c = hi;
  }
}

#define PUSHK(k_) { const uint32 kv_ = (k_); \
  p0=(nc==0)?kv_:p0;  p1=(nc==1)?kv_:p1;  p2=(nc==2)?kv_:p2; \
  p3=(nc==3)?kv_:p3;  p4=(nc==4)?kv_:p4;  p5=(nc==5)?kv_:p5; \
  p6=(nc==6)?kv_:p6;  p7=(nc==7)?kv_:p7;  p8=(nc==8)?kv_:p8; \
  p9=(nc==9)?kv_:p9;  p10=(nc==10)?kv_:p10; p11=(nc==11)?kv_:p11; \
  ++nc; }

#define DRAINALL { \
  if (__any(nc >  0)) { if (nc >  0) chain15(td, p0);  } \
  if (__any(nc >  1)) { if (nc >  1) chain15(td, p1);  } \
  if (__any(nc >  2)) { if (nc >  2) chain15(td, p2);  } \
  if (__any(nc >  3)) { if (nc >  3) chain15(td, p3);  } \
  if (__any(nc >  4)) { if (nc >  4) chain15(td, p4);  } \
  if (__any(nc >  5)) { if (nc >  5) chain15(td, p5);  } \
  if (__any(nc >  6)) { if (nc >  6) chain15(td, p6);  } \
  if (__any(nc >  7)) { if (nc >  7) chain15(td, p7);  } \
  if (__any(nc >  8)) { if (nc >  8) chain15(td, p8);  } \
  if (__any(nc >  9)) { if (nc >  9) chain15(td, p9);  } \
  if (__any(nc > 10)) { if (nc > 10) chain15(td, p10); } \
  if (__any(nc > 11)) { if (nc > 11) chain15(td, p11); } \
  nc = 0; guard = min(tau_cur, td[14]); }

// ---------------------------------------------------------------- prep
__global__ __launch_bounds__(256) void prep_kernel(
    const float* __restrict__ E, float* __restrict__ sqn,
    ushort* __restrict__ EA, ushort* __restrict__ EB) {
  const int row  = blockIdx.x * 4 + (threadIdx.x >> 6);
  const int lane = threadIdx.x & 63;
  const float SR2 = 1.4142135623730951f;
  float s = 0.f;
#pragma unroll
  for (int c = 0; c < 8; ++c) {
    const int d0 = lane + 64 * c;
    const float x = E[(size_t)row * DIM + d0];
    s = fmaf(x, x, s);
    __hip_bfloat16 ha = __float2bfloat16(-SR2 * x);
    __hip_bfloat16 hb = __float2bfloat16( SR2 * x);
    EA[(size_t)row * DIM + d0] = *(ushort*)&ha;
    EB[(size_t)row * DIM + d0] = *(ushort*)&hb;
  }
  s = wave_sum_f(s);
  if (lane == 0) sqn[row] = s;
}

// ---------------------------------------------------------------- probe
// One 128x128 subtile of the j<1024 region per block (grid 64x8 = 512
// blocks, 2/CU). Writes per-row sorted top-15 key list (slot = subtile).
// These 8 sub-lists ARE the candidate lists for splits 0-1 (union of
// subtile-top-15s contains the region top-15) and feed knn_main's tau.
__global__ __launch_bounds__(256, 4) void knn_probe(
    const ushort* __restrict__ EA, const ushort* __restrict__ EB,
    const float* __restrict__ sqn, uint32* __restrict__ knnk) {
  __shared__ __align__(16) char sm[KNN_LDS];
  uint32* sdp  = (uint32*)sm;
  float*  sqjs = (float*)(sm + SQJ_OFF);

  const int tid = threadIdx.x;
  const int w   = tid >> 6;
  const int L   = tid & 63;
  const int wr  = (w >> 1) & 1;
  const int wc  = w & 1;
  const int i0  = blockIdx.x * NI;
  const int j0p = blockIdx.y * JS;     // 0..896

  if (tid < 32) ((float4*)sqjs)[tid] = ((const float4*)(sqn + j0p))[tid];

  const ushort* gsrc = (w < 2) ? EA : EB;
  const int lrow  = L >> 2;
  const int swz_k = ((L & 3) ^ ((L >> 3) & 3)) * 8;
  const int lds_woff = ((w < 2) ? 0 : 8192) + (w & 1) * 4096;
  const int slot8 = (((L >> 4) ^ ((L >> 1) & 3)) * 8);

  const int myrow = tid >> 1;
  const int h     = tid & 1;
  const int gi    = i0 + myrow;

  uint32 td[15];
#pragma unroll
  for (int p = 0; p < 15; ++p) td[p] = EMPTYK;

  const int trowW = ((w < 2) ? i0 : j0p) + (w & 1) * 64;
  const ushort* gbase = gsrc + (size_t)(trowW + lrow) * DIM + swz_k;

  f32x4 acc[4][4];
  __syncthreads();
#pragma unroll
  for (int fj = 0; fj < 4; ++fj) {
    const f32x4 sq = *(const f32x4*)&sqjs[wc * 64 + fj * 16 + (L >> 4) * 4];
#pragma unroll
    for (int fi = 0; fi < 4; ++fi) acc[fj][fi] = sq;
  }

  {
    char* lp = sm + BUF0_OFF + lds_woff;
#pragma unroll
    for (int s = 0; s < 4; ++s)
      load_lds16(gbase + (size_t)(s * 16) * DIM, lp + s * 1024);
  }
  __syncthreads();

#pragma unroll 2
  for (int ch = 0; ch < NCH; ++ch) {
    const int cb  = (ch & 1) ? BUF1_OFF : BUF0_OFF;
    const int nbo = (ch & 1) ? BUF0_OFF : BUF1_OFF;
    if (ch < NCH - 1) {
      char* lp = sm + nbo + lds_woff;
      const ushort* gp = gbase + (ch + 1) * BK;
#pragma unroll
      for (int s = 0; s < 4; ++s)
        load_lds16(gp + (size_t)(s * 16) * DIM, lp + s * 1024);
    }

    const ushort* sA = (const ushort*)(sm + cb);
    const ushort* sB = (const ushort*)(sm + cb + 8192);

    short8 a[4], b[4];
#pragma unroll
    for (int f = 0; f < 4; ++f) {
      a[f] = *(const short8*)&sA[(wr * 64 + f * 16 + (L & 15)) * BK + slot8];
      b[f] = *(const short8*)&sB[(wc * 64 + f * 16 + (L & 15)) * BK + slot8];
    }
#pragma unroll
    for (int fj = 0; fj < 4; ++fj)
#pragma unroll
      for (int fi = 0; fi < 4; ++fi)
        acc[fj][fi] = __builtin_amdgcn_mfma_f32_16x16x32_bf16(b[fj], a[fi], acc[fj][fi], 0, 0, 0);
    __syncthreads();
  }

#pragma unroll
  for (int fj = 0; fj < 4; ++fj)
#pragma unroll
    for (int fi = 0; fi < 4; ++fi) {
      const int i_t = wr * 64 + fi * 16 + (L & 15);
      const int jd  = wc * 32 + fj * 8 + (L >> 4) * 2;
      uint32 dw0, dw1;
      asm("v_cvt_pk_bf16_f32 %0, %1, %2" : "=v"(dw0) : "v"(acc[fj][fi][0]), "v"(acc[fj][fi][1]));
      asm("v_cvt_pk_bf16_f32 %0, %1, %2" : "=v"(dw1) : "v"(acc[fj][fi][2]), "v"(acc[fj][fi][3]));
      uint2 d2; d2.x = dw0; d2.y = dw1;
      *(uint2*)&sdp[i_t * SDW + jd] = d2;
    }
  __syncthreads();

  // ---- scan (no external tau; guard = running td[14])
  uint32 tau_cur = EMPTYK;
  const int selfc = gi - j0p;
  if (selfc >= 0 && selfc < JS && h == (selfc >> 6))
    *(ushort*)(sm + myrow * (SDW * 4) + selfc * 2) = 0x7F80;

  const uint32* rowp = sdp + myrow * SDW + 32 * h;
  const uint32 jb = (uint32)(j0p + 64 * h);
  uint32 guard = min(tau_cur, td[14]);
  uint32 nc = 0;
  uint32 p0=0,p1=0,p2=0,p3=0,p4=0,p5=0,p6=0,p7=0,p8=0,p9=0,p10=0,p11=0;

#pragma unroll 2
  for (int q = 0; q < 8; ++q) {
    const uint4 pv = *(const uint4*)&rowp[4 * q];
    const uint32 jq = jb + 8 * q;
    uint32 kx;
    kx = (pv.x << 16)          | (jq + 0); if (kx < guard) PUSHK(kx);
    kx = (pv.x & 0xFFFF0000u)  | (jq + 1); if (kx < guard) PUSHK(kx);
    kx = (pv.y << 16)          | (jq + 2); if (kx < guard) PUSHK(kx);
    kx = (pv.y & 0xFFFF0000u)  | (jq + 3); if (kx < guard) PUSHK(kx);
    kx = (pv.z << 16)          | (jq + 4); if (kx < guard) PUSHK(kx);
    kx = (pv.z & 0xFFFF0000u)  | (jq + 5); if (kx < guard) PUSHK(kx);
    kx = (pv.w << 16)          | (jq + 6); if (kx < guard) PUSHK(kx);
    kx = (pv.w & 0xFFFF0000u)  | (jq + 7); if (kx < guard) PUSHK(kx);
    if (__any(nc >= 4)) { DRAINALL; }
  }
  if (__any(nc > 0)) { DRAINALL; }
  __syncthreads();

  // ---- pair-merge -> sorted top-15 of the 128-subtile, slot = blockIdx.y
  uint32* mdk = (uint32*)sm;
#pragma unroll
  for (int p = 0; p < 15; ++p) mdk[(myrow * 2 + h) * 15 + p] = td[p];
  __syncthreads();
  if (h == 0) {
    const uint32* la = &mdk[(myrow * 2 + 0) * 15];
    const uint32* lb = &mdk[(myrow * 2 + 1) * 15];
    int pa = 0, pb = 0;
    const size_t base = ((size_t)gi * NLIST + blockIdx.y) * KNNK;
    for (int s = 0; s < KNNK; ++s) {
      const uint32 va = la[pa], vb = lb[pb];
      uint32 v;
      if (va <= vb) { v = va; ++pa; } else { v = vb; ++pb; }
      knnk[base + s] = v;
    }
  }
}

// ---------------------------------------------------------------- main
// Splits 2..15 with tau derived from the 8 probe lists: pairwise exact
// 15th-of-union (two-sorted-arrays selection, static unroll) -> min of 4
// + margin. Tighter than R7's min-of-split-15ths.
__global__ __launch_bounds__(256, 4) void knn_main(
    const ushort* __restrict__ EA, const ushort* __restrict__ EB,
    const float* __restrict__ sqn, uint32* __restrict__ knnk) {
  __shared__ __align__(16) char sm[KNN_LDS];
  uint32* sdp  = (uint32*)sm;
  float*  sqjs = (float*)(sm + SQJ_OFF);

  const int tid = threadIdx.x;
  const int w   = tid >> 6;
  const int L   = tid & 63;
  const int wr  = (w >> 1) & 1;
  const int wc  = w & 1;
  const int i0  = blockIdx.x * NI;
  const int jsplit = blockIdx.y + 2;     // splits 2..15
  const int j0  = jsplit * NJ;

  if (tid < NJ / 4) ((float4*)sqjs)[tid] = ((const float4*)(sqn + j0))[tid];

  const ushort* gsrc = (w < 2) ? EA : EB;
  const int lrow  = L >> 2;
  const int swz_k = ((L & 3) ^ ((L >> 3) & 3)) * 8;
  const int lds_woff = ((w < 2) ? 0 : 8192) + (w & 1) * 4096;
  const int slot8 = (((L >> 4) ^ ((L >> 1) & 3)) * 8);

  const int myrow = tid >> 1;
  const int h     = tid & 1;
  const int gi    = i0 + myrow;

  // ---- tau from probe lists: min over 4 pairwise 15th-of-union + margin
  uint32 tauA;
  {
    const uint32* lb0 = knnk + (size_t)gi * NKEYS;
    uint32 tmin = EMPTYK;
#pragma unroll
    for (int pr = 0; pr < 4; ++pr) {
      const uint32* A = lb0 + (2 * pr) * KNNK;
      const uint32* B = lb0 + (2 * pr + 1) * KNNK;
      uint32 a[15], b[15];
#pragma unroll
      for (int k = 0; k < 15; ++k) { a[k] = A[k]; b[k] = B[k]; }
      // 15th smallest of A  B (both sorted asc): min_i max(A[i-1], B[14-i])
      uint32 v = min(b[14], a[14]);
#pragma unroll
      for (int i2 = 1; i2 <= 14; ++i2) v = min(v, max(a[i2 - 1], b[14 - i2]));
      tmin = min(tmin, v);
    }
    tauA = tmin + TAU_MARGIN;
  }

  uint32 td[15];
#pragma unroll
  for (int p = 0; p < 15; ++p) td[p] = EMPTYK;

  __syncthreads();

  for (int js = 0; js < NSUB; ++js) {
    const int jrow0 = j0 + js * JS;
    const int trowW = ((w < 2) ? i0 : jrow0) + (w & 1) * 64;
    const ushort* gbase = gsrc + (size_t)(trowW + lrow) * DIM + swz_k;

    f32x4 acc[4][4];
#pragma unroll
    for (int fj = 0; fj < 4; ++fj) {
      const f32x4 sq = *(const f32x4*)&sqjs[js * 128 + wc * 64 + fj * 16 + (L >> 4) * 4];
#pragma unroll
      for (int fi = 0; fi < 4; ++fi) acc[fj][fi] = sq;
    }

    {
      char* lp = sm + BUF0_OFF + lds_woff;
#pragma unroll
      for (int s = 0; s < 4; ++s)
        load_lds16(gbase + (size_t)(s * 16) * DIM, lp + s * 1024);
    }
    __syncthreads();

#pragma unroll 2
    for (int ch = 0; ch < NCH; ++ch) {
      const int cb  = (ch & 1) ? BUF1_OFF : BUF0_OFF;
      const int nbo = (ch & 1) ? BUF0_OFF : BUF1_OFF;
      if (ch < NCH - 1) {
        char* lp = sm + nbo + lds_woff;
        const ushort* gp = gbase + (ch + 1) * BK;
#pragma unroll
        for (int s = 0; s < 4; ++s)
          load_lds16(gp + (size_t)(s * 16) * DIM, lp + s * 1024);
      }

      const ushort* sA = (const ushort*)(sm + cb);
      const ushort* sB = (const ushort*)(sm + cb + 8192);

      short8 a[4], b[4];
#pragma unroll
      for (int f = 0; f < 4; ++f) {
        a[f] = *(const short8*)&sA[(wr * 64 + f * 16 + (L & 15)) * BK + slot8];
        b[f] = *(const short8*)&sB[(wc * 64 + f * 16 + (L & 15)) * BK + slot8];
      }
#pragma unroll
      for (int fj = 0; fj < 4; ++fj)
#pragma unroll
        for (int fi = 0; fi < 4; ++fi)
          acc[fj][fi] = __builtin_amdgcn_mfma_f32_16x16x32_bf16(b[fj], a[fi], acc[fj][fi], 0, 0, 0);
      __syncthreads();
    }

#pragma unroll
    for (int fj = 0; fj < 4; ++fj)
#pragma unroll
      for (int fi = 0; fi < 4; ++fi) {
        const int i_t = wr * 64 + fi * 16 + (L & 15);
        const int jd  = wc * 32 + fj * 8 + (L >> 4) * 2;
        uint32 dw0, dw1;
        asm("v_cvt_pk_bf16_f32 %0, %1, %2" : "=v"(dw0) : "v"(acc[fj][fi][0]), "v"(acc[fj][fi][1]));
        asm("v_cvt_pk_bf16_f32 %0, %1, %2" : "=v"(dw1) : "v"(acc[fj][fi][2]), "v"(acc[fj][fi][3]));
        uint2 d2; d2.x = dw0; d2.y = dw1;
        *(uint2*)&sdp[i_t * SDW + jd] = d2;
      }
    __syncthreads();

    // ---- scan: guard = min(tau, running 15th)
    uint32 tau_cur = tauA;
    const int selfc = gi - jrow0;
    if (selfc >= 0 && selfc < JS && h == (selfc >> 6))
      *(ushort*)(sm + myrow * (SDW * 4) + selfc * 2) = 0x7F80;

    const uint32* rowp = sdp + myrow * SDW + 32 * h;
    const uint32 jb = (uint32)(jrow0 + 64 * h);
    uint32 guard = min(tau_cur, td[14]);
    uint32 nc = 0;
    uint32 p0=0,p1=0,p2=0,p3=0,p4=0,p5=0,p6=0,p7=0,p8=0,p9=0,p10=0,p11=0;

#pragma unroll 2
    for (int q = 0; q < 8; ++q) {
      const uint4 pv = *(const uint4*)&rowp[4 * q];
      const uint32 jq = jb + 8 * q;
      uint32 kx;
      kx = (pv.x << 16)          | (jq + 0); if (kx < guard) PUSHK(kx);
      kx = (pv.x & 0xFFFF0000u)  | (jq + 1); if (kx < guard) PUSHK(kx);
      kx = (pv.y << 16)          | (jq + 2); if (kx < guard) PUSHK(kx);
      kx = (pv.y & 0xFFFF0000u)  | (jq + 3); if (kx < guard) PUSHK(kx);
      kx = (pv.z << 16)          | (jq + 4); if (kx < guard) PUSHK(kx);
      kx = (pv.z & 0xFFFF0000u)  | (jq + 5); if (kx < guard) PUSHK(kx);
      kx = (pv.w << 16)          | (jq + 6); if (kx < guard) PUSHK(kx);
      kx = (pv.w & 0xFFFF0000u)  | (jq + 7); if (kx < guard) PUSHK(kx);
      if (__any(nc >= 4)) { DRAINALL; }
    }
    if (__any(nc > 0)) { DRAINALL; }
    __syncthreads();
  }

  // ---- pair-merge -> top-15 per (row, split); slot 8 + blockIdx.y
  uint32* mdk = (uint32*)sm;
#pragma unroll
  for (int p = 0; p < 15; ++p) mdk[(myrow * 2 + h) * 15 + p] = td[p];
  __syncthreads();
  if (h == 0) {
    const uint32* la = &mdk[(myrow * 2 + 0) * 15];
    const uint32* lb = &mdk[(myrow * 2 + 1) * 15];
    int pa = 0, pb = 0;
    const size_t base = ((size_t)gi * NLIST + NPROBE + blockIdx.y) * KNNK;
    for (int s = 0; s < KNNK; ++s) {
      const uint32 va = la[pa], vb = lb[pb];
      uint32 v;
      if (va <= vb) { v = va; ++pa; } else { v = vb; ++pb; }
      knnk[base + s] = v;
    }
  }
}

// ---------------------------------------------------------------- sig
// Merge 330 keys (22 lists) -> approx top-NCAND -> EXACT fp32 refine ->
// exact top-15 -> curvature -> gram -> bitonic-128 -> per-wave partial.
__global__ __launch_bounds__(256) void sig_kernel(
    const float* __restrict__ E, const uint32* __restrict__ knnk,
    const float* __restrict__ refc, const float* __restrict__ refa,
    float2* __restrict__ pacc) {
  __shared__ float gsm[4][292];

  const int tid = threadIdx.x;
  const int wid = tid >> 6;
  const int L   = tid & 63;
  const int i   = blockIdx.x * 4 + wid;

  const uint32* kl = knnk + (size_t)i * NKEYS;   // 330 keys
  uint32 k0 = kl[L];
  uint32 k1 = kl[L + 64];
  uint32 k2 = kl[L + 128];
  uint32 k3 = kl[L + 192];
  uint32 k4 = kl[L + 256];                       // 256..319 < 330
  uint32 k5 = (L < NKEYS - 320) ? kl[L + 320] : EMPTYK;
  uint32 cand_key = EMPTYK;
  for (int sel = 0; sel < NCAND; ++sel) {
    uint32 v = k0; int which = 0;
    if (k1 < v) { v = k1; which = 1; }
    if (k2 < v) { v = k2; which = 2; }
    if (k3 < v) { v = k3; which = 3; }
    if (k4 < v) { v = k4; which = 4; }
    if (k5 < v) { v = k5; which = 5; }
    int slot = (L << 3) | which;
#pragma unroll
    for (int off = 32; off > 0; off >>= 1) {
      const uint32 ov = (uint32)__shfl_down((int)v, off, 64);
      const int    os = __shfl_down(slot, off, 64);
      if (ov < v) { v = ov; slot = os; }
    }
    const uint32 vmin = (uint32)__shfl((int)v, 0, 64);
    const int    smin = __shfl(slot, 0, 64);
    if (L == sel) cand_key = vmin;
    if (L == (smin >> 3)) {
      const int wsel = smin & 7;
      if (wsel == 0) k0 = EMPTYK;
      else if (wsel == 1) k1 = EMPTYK;
      else if (wsel == 2) k2 = EMPTYK;
      else if (wsel == 3) k3 = EMPTYK;
      else if (wsel == 4) k4 = EMPTYK;
      else k5 = EMPTYK;
    }
  }
  int cand_nb = ((cand_key >> 16) < 0x7F80u) ? (int)(cand_key & 0x1FFFu) : i;

  // ---- exact refine
  const float4* ei4 = (const float4*)(E + (size_t)i * DIM);
  const float4 e0 = ei4[2 * L];
  const float4 e1 = ei4[2 * L + 1];
  float csq = CINF;
#pragma unroll 2
  for (int c = 0; c < NCAND; ++c) {
    const int row = __shfl(cand_nb, c, 64);
    const float4* r4 = (const float4*)(E + (size_t)row * DIM);
    const float4 a0 = r4[2 * L];
    const float4 a1 = r4[2 * L + 1];
    const float d0 = a0.x - e0.x, d1 = a0.y - e0.y;
    const float d2 = a0.z - e0.z, d3 = a0.w - e0.w;
    const float d4 = a1.x - e1.x, d5 = a1.y - e1.y;
    const float d6 = a1.z - e1.z, d7 = a1.w - e1.w;
    float s8 = d0 * d0;
    s8 = fmaf(d1, d1, s8); s8 = fmaf(d2, d2, s8); s8 = fmaf(d3, d3, s8);
    s8 = fmaf(d4, d4, s8); s8 = fmaf(d5, d5, s8); s8 = fmaf(d6, d6, s8);
    s8 = fmaf(d7, d7, s8);
    const float sq = wave_sum_f(s8);
    if (L == c) csq = (row == i) ? CINF : sq;
  }

  // ---- exact top-15
  float myd = 0.f; int mynb = i;
  for (int sel = 0; sel < KNNK; ++sel) {
    float v = csq; int who = L;
#pragma unroll
    for (int off = 32; off > 0; off >>= 1) {
      const float ov = __shfl_down(v, off, 64);
      const int   ow = __shfl_down(who, off, 64);
      if (ov < v) { v = ov; who = ow; }
    }
    const float vmin  = __shfl(v, 0, 64);
    const int   wmin  = __shfl(who, 0, 64);
    const int   nbmin = __shfl(cand_nb, wmin, 64);
    if ((L & 15) == sel) { myd = sqrtf(fmaxf(vmin, 1e-12f)); mynb = nbmin; }
    if (L == wmin) csq = CINF;
  }

  // ---- curvature
  float curvs;
  {
    float dd = (L < KNNK) ? myd : 0.f;
    float tot = wave_sum_f(dd);
    float mean_d = tot / (float)KNNK + 1e-8f;
    float diff = (L < KNNK) ? (dd / mean_d - refc[i * KNNK + L]) : 0.f;
    curvs = wave_sum_f(diff * diff);
  }

  // ---- gram of raw neighbor differences
  const float4* nb4 = (const float4*)(E + (size_t)mynb * DIM);
  const int qo = (L >> 4) * 2;

  f32x4 gH, gX;
#pragma unroll
  for (int r = 0; r < 4; ++r) { gH[r] = 0.f; gX[r] = 0.f; }

#pragma unroll
  for (int c = 0; c < 16; ++c) {
    const float4 f0 = nb4[qo + c * 8];
    const float4 f1 = nb4[qo + 1 + c * 8];
    const float4 g0 = ei4[qo + c * 8];
    const float4 g1 = ei4[qo + 1 + c * 8];
    float v[8];
    v[0] = f0.x - g0.x; v[1] = f0.y - g0.y; v[2] = f0.z - g0.z; v[3] = f0.w - g0.w;
    v[4] = f1.x - g1.x; v[5] = f1.y - g1.y; v[6] = f1.z - g1.z; v[7] = f1.w - g1.w;
    short8 ah, al;
#pragma unroll
    for (int q = 0; q < 8; ++q) {
      short hh, ll;
      bf16split(v[q], hh, ll);
      ah[q] = hh; al[q] = ll;
    }
    gH = __builtin_amdgcn_mfma_f32_16x16x32_bf16(ah, ah, gH, 0, 0, 0);
    gX = __builtin_amdgcn_mfma_f32_16x16x32_bf16(ah, al, gX, 0, 0, 0);
    gX = __builtin_amdgcn_mfma_f32_16x16x32_bf16(al, ah, gX, 0, 0, 0);
  }

#pragma unroll
  for (int q = 0; q < 4; ++q)
    gsm[wid][((L >> 4) * 4 + q) * 17 + (L & 15)] = gH[q] + gX[q];
  asm volatile("s_waitcnt lgkmcnt(0)" ::: "memory");

  if (L < 16) {
    const float dv = gsm[wid][L * 17 + L];
    const float nrm = sqrtf(fmaxf(dv, 0.f));
    gsm[wid][272 + L] = 1.0f / fmaxf(nrm, 1e-8f);
  }
  asm volatile("s_waitcnt lgkmcnt(0)" ::: "memory");

  float c0 = CINF, c1 = CINF;
#pragma unroll
  for (int s = 0; s < 2; ++s) {
    const int p = L + 64 * s;
    if (p < NPAIR) {
      int a = 0, rem = p, cnt = 14;
      while (rem >= cnt) { rem -= cnt; --cnt; ++a; }
      const int b = a + 1 + rem;
      const float cv = gsm[wid][a * 17 + b] * gsm[wid][272 + a] * gsm[wid][272 + b];
      if (s == 0) c0 = cv; else c1 = cv;
    }
  }

#pragma unroll
  for (int k = 2; k <= 128; k <<= 1) {
#pragma unroll
    for (int j = k >> 1; j >= 1; j >>= 1) {
      const bool dir = ((L & (k >> 1)) == 0);
      if (j == 1) {
        const float lo = fminf(c0, c1), hi = fmaxf(c0, c1);
        c0 = dir ? lo : hi;
        c1 = dir ? hi : lo;
      } else {
        const int m = j >> 1;
        const float o0 = __shfl_xor(c0, m, 64);
        const float o1 = __shfl_xor(c1, m, 64);
        const bool lower = ((L & m) == 0);
        c0 = (lower == dir) ? fminf(c0, o0) : fmaxf(c0, o0);
        c1 = (lower == dir) ? fminf(c1, o1) : fmaxf(c1, o1);
      }
    }
  }

  float part = 0.f;
  {
    const int r0 = 2 * L, r1 = 2 * L + 1;
    if (r0 < NPAIR) { const float dd = c0 - refa[(size_t)i * NPAIR + r0]; part += dd * dd; }
    if (r1 < NPAIR) { const float dd = c1 - refa[(size_t)i * NPAIR + r1]; part += dd * dd; }
  }
  part = wave_sum_f(part);
  if (L == 0) pacc[i] = make_float2(curvs, part);
}

// ---------------------------------------------------------------- fin
__global__ __launch_bounds__(256) void fin_kernel(
    const float2* __restrict__ pacc, float* __restrict__ out) {
  __shared__ double redc[4], reda[4];
  const int tid = threadIdx.x;
  const int wid = tid >> 6;
  const int L   = tid & 63;
  double sc = 0.0, sa = 0.0;
#pragma unroll
  for (int q = 0; q < 32; ++q) {
    const float2 p = pacc[tid + 256 * q];
    sc += (double)p.x;
    sa += (double)p.y;
  }
#pragma unroll
  for (int m = 32; m > 0; m >>= 1) {
    sc += __shfl_xor(sc, m, 64);
    sa += __shfl_xor(sa, m, 64);
  }
  if (L == 0) { redc[wid] = sc; reda[wid] = sa; }
  __syncthreads();
  if (tid == 0) {
    const double curv = (redc[0] + redc[1] + redc[2] + redc[3]) /
                        ((double)NPTS * (double)KNNK);
    const double ang  = (reda[0] + reda[1] + reda[2] + reda[3]) /
                        ((double)NPTS * (double)NPAIR);
    out[0] = (float)(0.3 * curv + 0.7 * ang);
  }
}

// ---------------------------------------------------------------- launch
extern "C" void kernel_launch(void* const* d_in, const int* in_sizes, int n_in,
                              void* d_out, int out_size, void* d_ws,
                              size_t ws_size, hipStream_t stream) {
  const float* E    = (const float*)d_in[0];
  const float* refc = (const float*)d_in[1];
  const float* refa = (const float*)d_in[2];
  float* out = (float*)d_out;

  char* ws = (char*)d_ws;
  float*  sqn  = (float*)(ws + 1024);
  float2* pacc = (float2*)(ws + 65536);
  ushort* EA   = (ushort*)(ws + 1048576);
  ushort* EB   = (ushort*)(ws + 9437184);
  uint32* knnk = (uint32*)(ws + 17825792);    // [NPTS][22][15] keys (10.8 MB)

  prep_kernel<<<NPTS / 4, 256, 0, stream>>>(E, sqn, EA, EB);
  knn_probe<<<dim3(NPTS / NI, NPROBE), 256, 0, stream>>>(EA, EB, sqn, knnk);
  knn_main<<<dim3(NPTS / NI, NJSPLIT - 2), 256, 0, stream>>>(EA, EB, sqn, knnk);
  sig_kernel<<<NPTS / 4, 256, 0, stream>>>(E, knnk, refc, refa, pacc);
  fin_kernel<<<1, 256, 0, stream>>>(pacc, out);
}